// Round 5
// baseline (129987.073 us; speedup 1.0000x reference)
//
#include <hip/hip_runtime.h>
#include <hip/hip_bf16.h>

typedef __hip_bfloat16 bf16;
typedef unsigned short u16;
typedef unsigned char u8;

#define NB 8
#define CH 192

static __device__ __forceinline__ float bf2f(bf16 v){ return __bfloat162float(v); }

// ---------------- utility kernels ----------------

__global__ void k_zero(float* p, int n){
  int i = blockIdx.x*blockDim.x + threadIdx.x;
  if(i < n) p[i] = 0.f;
}

__global__ void k_fill(float* p, int n, float v){
  int i = blockIdx.x*blockDim.x + threadIdx.x;
  if(i < n) p[i] = v;
}

// m0[b,256,256] = 1 - mask[b, (y/16)*16 + (x/16)]   (mask: int32 0/1)
__global__ void k_mask0(const int* __restrict__ mask, u8* __restrict__ m0){
  int i = blockIdx.x*blockDim.x + threadIdx.x;
  if(i >= NB*65536) return;
  int b = i >> 16; int p = i & 65535;
  int y = p >> 8, x = p & 255;
  int patch = (y >> 4)*16 + (x >> 4);
  m0[i] = (u8)(1 - mask[b*256 + patch]);
}

// 3x3 stride-2 pad-1 max-pool of mask
__global__ void k_maskdown(const u8* __restrict__ mi, u8* __restrict__ mo,
                           int Ho, int Wo, int Hi, int Wi){
  int i = blockIdx.x*blockDim.x + threadIdx.x;
  int total = NB*Ho*Wo; if(i >= total) return;
  int b = i/(Ho*Wo); int p = i%(Ho*Wo);
  int oy = p/Wo, ox = p%Wo;
  u8 v = 0;
  for(int ky=0; ky<3; ky++){
    int iy = oy*2 + ky - 1; if(iy < 0 || iy >= Hi) continue;
    for(int kx=0; kx<3; kx++){
      int ix = ox*2 + kx - 1; if(ix < 0 || ix >= Wi) continue;
      u8 t = mi[(b*Hi + iy)*Wi + ix]; if(t > v) v = t;
    }
  }
  mo[i] = v;
}

__global__ void k_count(const u8* __restrict__ m, int n, float* cnt){
  int i = blockIdx.x*blockDim.x + threadIdx.x;
  int stride = gridDim.x*blockDim.x;
  int local = 0;
  for(int j=i; j<n; j+=stride) local += m[j];
  for(int o=32; o>0; o>>=1) local += __shfl_down(local, o, 64);
  if((threadIdx.x & 63) == 0 && local) atomicAdd(cnt, (float)local);
}

// ---------------- stem BN stats: block = (channel, pixel-chunk), images f32 ----------------

__global__ __launch_bounds__(256) void k_stemstats2(const float* __restrict__ im,
        const u8* __restrict__ m0, const float* __restrict__ sw,
        float* __restrict__ stats){
  int c = blockIdx.x;          // 0..191
  int chunk = blockIdx.y;      // 0..127, 4096 px each (8*65536 total)
  float w0 = sw[c*3+0], w1 = sw[c*3+1], w2 = sw[c*3+2];
  float s = 0.f, s2 = 0.f;
  int start = chunk*4096;
  for(int j = start + threadIdx.x; j < start + 4096; j += 256){
    if(m0[j]){
      int b = j >> 16, p = j & 65535;
      float d = w0*im[(size_t)(b*3+0)*65536 + p]
              + w1*im[(size_t)(b*3+1)*65536 + p]
              + w2*im[(size_t)(b*3+2)*65536 + p];
      s += d; s2 += d*d;
    }
  }
  for(int o=32; o>0; o>>=1){ s += __shfl_down(s, o, 64); s2 += __shfl_down(s2, o, 64); }
  __shared__ float sh[8];
  int w = threadIdx.x >> 6;
  if((threadIdx.x & 63) == 0){ sh[w] = s; sh[4+w] = s2; }
  __syncthreads();
  if(threadIdx.x == 0){
    float ts = 0.f, t2 = 0.f;
    for(int k=0;k<4;k++){ ts += sh[k]; t2 += sh[4+k]; }
    atomicAdd(&stats[c], ts);
    atomicAdd(&stats[CH + c], t2);
  }
}

// ---------------- weight repack: W[co,ci,3,3] f32 -> Wt[(ci*192+co)*12 + k] f32 ----------------

__global__ void k_repack(const float* __restrict__ w, float* __restrict__ wt){
  int i = blockIdx.x*blockDim.x + threadIdx.x;
  if(i >= CH*CH*9) return;
  int k = i % 9; int ci = (i/9) % CH; int co = i/(9*CH);
  wt[(ci*CH + co)*12 + k] = w[i];
}

// ---------------- direct 3x3 conv (all levels), thread per output; bf16 activations ----------------

template<int S>
__global__ void k_conv3d(const bf16* __restrict__ in, const float* __restrict__ wt,
                         const u8* __restrict__ mk, bf16* __restrict__ out, int Ho, int Wo){
  int i = blockIdx.x*blockDim.x + threadIdx.x;
  int HW = Ho*Wo;
  int total = NB*CH*HW; if(i >= total) return;
  int p = i % HW; int co = (i/HW) % CH; int b = i/(HW*CH);
  if(!mk[b*HW + p]) return;  // inactive output, masked later
  int oy = p / Wo, ox = p % Wo;
  int Hi = Ho*S, Wi = Wo*S;
  int iy0 = oy*S - 1, ix0 = ox*S - 1;
  float acc = 0.f;
  for(int ci=0; ci<CH; ci++){
    const bf16* ib = in + (size_t)((b*CH + ci)*Hi)*Wi;
    float w[9];
#pragma unroll
    for(int k=0;k<9;k++) w[k] = wt[(ci*CH + co)*12 + k];
#pragma unroll
    for(int ky=0; ky<3; ky++){
      int iy = iy0 + ky; if(iy < 0 || iy >= Hi) continue;
#pragma unroll
      for(int kx=0; kx<3; kx++){
        int ix = ix0 + kx; if(ix < 0 || ix >= Wi) continue;
        acc += w[ky*3+kx]*bf2f(ib[iy*Wi + ix]);
      }
    }
  }
  out[i] = __float2bfloat16(acc);
}

// ---------------- stage-0 down conv with on-the-fly stem (1x1 f32 conv + BN + ReLU) ----------------

__global__ void k_conv0d(const float* __restrict__ im, const float* __restrict__ sw,
                         const float* __restrict__ ssA, const u8* __restrict__ m0,
                         const float* __restrict__ wt, const u8* __restrict__ mk,
                         bf16* __restrict__ out){
  int i = blockIdx.x*blockDim.x + threadIdx.x;
  const int HW = 16384;  // 128*128
  if(i >= NB*CH*HW) return;
  int p = i % HW; int co = (i/HW) % CH; int b = i/(HW*CH);
  if(!mk[b*HW + p]) return;
  int oy = p >> 7, ox = p & 127;
  int iy0 = oy*2 - 1, ix0 = ox*2 - 1;
  const float* imr = im + (size_t)(b*3+0)*65536;
  const float* img = im + (size_t)(b*3+1)*65536;
  const float* imb = im + (size_t)(b*3+2)*65536;
  const u8* m0b = m0 + b*65536;
  float acc = 0.f;
  for(int ci=0; ci<CH; ci++){
    float w[9];
#pragma unroll
    for(int k=0;k<9;k++) w[k] = wt[(ci*CH + co)*12 + k];
    float w0 = sw[ci*3+0], w1 = sw[ci*3+1], w2 = sw[ci*3+2];
    float sc = ssA[ci], sh = ssA[CH+ci];
#pragma unroll
    for(int ky=0; ky<3; ky++){
      int iy = iy0 + ky; if(iy < 0 || iy >= 256) continue;
#pragma unroll
      for(int kx=0; kx<3; kx++){
        int ix = ix0 + kx; if(ix < 0 || ix >= 256) continue;
        int pi = iy*256 + ix;
        if(!m0b[pi]) continue;   // stem output is exactly 0 at inactive sites
        float d = w0*imr[pi] + w1*img[pi] + w2*imb[pi];
        float a = fmaxf(sc*d + sh, 0.f);
        acc += w[ky*3+kx]*a;
      }
    }
  }
  out[i] = __float2bfloat16(acc);
}

// ---------------- masked BN: stats / finalize / apply ----------------

__global__ void k_bnstats(const bf16* __restrict__ x, const u8* __restrict__ m,
                          float* __restrict__ stats, int HW){
  int c = blockIdx.x;
  int nchunk = gridDim.y;
  int nper = (NB*HW + nchunk - 1)/nchunk;
  int start = blockIdx.y*nper;
  int end = start + nper; if(end > NB*HW) end = NB*HW;
  float s = 0.f, s2 = 0.f;
  for(int i = start + threadIdx.x; i < end; i += blockDim.x){
    int b = i / HW, p = i % HW;
    if(m[b*HW + p]){
      float v = bf2f(x[(size_t)(b*CH + c)*HW + p]);
      s += v; s2 += v*v;
    }
  }
  for(int o=32; o>0; o>>=1){ s += __shfl_down(s, o, 64); s2 += __shfl_down(s2, o, 64); }
  __shared__ float sh[8];
  int w = threadIdx.x >> 6;
  if((threadIdx.x & 63) == 0){ sh[w] = s; sh[4+w] = s2; }
  __syncthreads();
  if(threadIdx.x == 0){
    float ts = 0.f, t2 = 0.f;
    int nw = blockDim.x >> 6;
    for(int k=0;k<nw;k++){ ts += sh[k]; t2 += sh[4+k]; }
    atomicAdd(&stats[c], ts);
    atomicAdd(&stats[CH + c], t2);
  }
}

__global__ void k_bnfinal(const float* __restrict__ stats, const float* __restrict__ cnt,
                          const float* __restrict__ g, const float* __restrict__ bb,
                          float* __restrict__ ss){
  int c = threadIdx.x; if(c >= CH) return;
  float n = fmaxf(*cnt, 1.0f);
  float mean = stats[c]/n;
  float var = stats[CH + c]/n - mean*mean;
  var = fmaxf(var, 0.f);
  float rstd = rsqrtf(var + 1e-5f);
  float sc = g[c]*rstd;
  ss[c] = sc;
  ss[CH + c] = bb[c] - mean*sc;
}

template<int RELU, int ADD>
__global__ void k_bnapply(const bf16* __restrict__ x, const u8* __restrict__ m,
                          const float* __restrict__ ss, const bf16* __restrict__ idn,
                          bf16* __restrict__ out, int HW){
  int i = blockIdx.x*blockDim.x + threadIdx.x;
  int total = NB*CH*HW; if(i >= total) return;
  int p = i % HW; int c = (i/HW) % CH; int b = i/(HW*CH);
  float v = bf2f(x[i])*ss[c] + ss[CH + c];
  v *= (float)m[b*HW + p];
  if(ADD) v += bf2f(idn[i]);
  if(RELU) v = fmaxf(v, 0.f);
  out[i] = __float2bfloat16(v);
}

// final BN apply: relu, no add, float32 output (x region of d_out)
__global__ void k_bnapply_out(const bf16* __restrict__ x, const u8* __restrict__ m,
                              const float* __restrict__ ss, float* __restrict__ out, int HW){
  int i = blockIdx.x*blockDim.x + threadIdx.x;
  int total = NB*CH*HW; if(i >= total) return;
  int p = i % HW; int c = (i/HW) % CH; int b = i/(HW*CH);
  float v = bf2f(x[i])*ss[c] + ss[CH + c];
  v *= (float)m[b*HW + p];
  v = fmaxf(v, 0.f);
  out[i] = v;
}

// ---------------- final 1x1 conv (192 -> 192) at 16x16 ----------------

__global__ void k_final(const bf16* __restrict__ in, const float* __restrict__ w,
                        const u8* __restrict__ m4, bf16* __restrict__ out){
  int i = blockIdx.x*blockDim.x + threadIdx.x;
  if(i >= NB*CH*256) return;
  int p = i & 255; int co = (i >> 8) % CH; int b = i/(256*CH);
  if(!m4[b*256 + p]) return;
  float acc = 0.f;
  for(int ci=0; ci<CH; ci++)
    acc += w[co*CH + ci]*bf2f(in[(b*CH + ci)*256 + p]);
  out[i] = __float2bfloat16(acc);
}

// ---------------- tail: mask + ids_restore outputs (float32) ----------------

__global__ void k_tail(const int* __restrict__ mask, float* __restrict__ out){
  int i = blockIdx.x*blockDim.x + threadIdx.x;
  if(i < 2048){
    out[393216 + i] = (float)mask[i];
  } else if(i < 4096){
    int j = i - 2048;
    out[395264 + j] = (float)(j & 255);
  }
}

// ---------------- host orchestration ----------------

extern "C" void kernel_launch(void* const* d_in, const int* in_sizes, int n_in,
                              void* d_out, int out_size, void* d_ws, size_t ws_size,
                              hipStream_t stream){
  const float* images = (const float*)d_in[0];
  const int*   maskI  = (const int*)d_in[1];
  const float* stem_w = (const float*)d_in[2];
  const float* stem_g = (const float*)d_in[3];
  const float* stem_b = (const float*)d_in[4];
  const float* dw1 = (const float*)d_in[5];
  const float* dg1 = (const float*)d_in[6];
  const float* db1 = (const float*)d_in[7];
  const float* dw2 = (const float*)d_in[8];
  const float* dg2 = (const float*)d_in[9];
  const float* db2 = (const float*)d_in[10];
  const float* rw1 = (const float*)d_in[11];
  const float* rg1 = (const float*)d_in[12];
  const float* rb1 = (const float*)d_in[13];
  const float* rw2 = (const float*)d_in[14];
  const float* rg2 = (const float*)d_in[15];
  const float* rb2 = (const float*)d_in[16];
  const float* final_w = (const float*)d_in[17];
  const float* final_g = (const float*)d_in[18];
  const float* final_b = (const float*)d_in[19];
  float* outF = (float*)d_out;

  // workspace carve (~154 MB); activations stored bf16 internally
  char* wsp = (char*)d_ws;
  auto alloc = [&](size_t bytes)->char*{
    char* p = wsp; wsp += (bytes + 255) & ~(size_t)255; return p;
  };
  bf16* S0 = (bf16*)alloc((size_t)NB*CH*16384*2);
  bf16* S1 = (bf16*)alloc((size_t)NB*CH*16384*2);
  bf16* S2 = (bf16*)alloc((size_t)NB*CH*16384*2);
  int Hs[5] = {256,128,64,32,16};
  u8* M[5];
  for(int l=0;l<5;l++) M[l] = (u8*)alloc((size_t)NB*Hs[l]*Hs[l]);
  float* Wt = (float*)alloc((size_t)CH*CH*12*4);
  float* stats = (float*)alloc(2*CH*4);
  float* ss    = (float*)alloc(2*CH*4);
  float* ssA   = (float*)alloc(2*CH*4);
  float* cnts  = (float*)alloc(8*4);
  size_t need = (size_t)(wsp - (char*)d_ws);

  // fallback with DISTINCT signature (777): if this shows up as ~777 absmax,
  // workspace is too small — unambiguous vs any compute bug.
  if(ws_size < need){
    k_fill<<<(393216+255)/256, 256, 0, stream>>>(outF, 393216, 777.0f);
    k_tail<<<16, 256, 0, stream>>>(maskI, outF);
    return;
  }

  // ---- mask pyramid + counts ----
  k_mask0<<<(NB*65536+255)/256, 256, 0, stream>>>(maskI, M[0]);
  for(int l=1;l<5;l++){
    int total = NB*Hs[l]*Hs[l];
    k_maskdown<<<(total+255)/256, 256, 0, stream>>>(M[l-1], M[l], Hs[l], Hs[l], Hs[l-1], Hs[l-1]);
  }
  k_zero<<<1, 32, 0, stream>>>(cnts, 8);
  for(int l=0;l<5;l++){
    int n = NB*Hs[l]*Hs[l];
    int blocks = (n + 256*64 - 1)/(256*64); if(blocks < 1) blocks = 1; if(blocks > 256) blocks = 256;
    k_count<<<blocks, 256, 0, stream>>>(M[l], n, cnts + l);
  }

  // ---- stem BN params (stats computed on the fly, nothing materialized) ----
  k_zero<<<2, 256, 0, stream>>>(stats, 2*CH);
  k_stemstats2<<<dim3(CH, 128), 256, 0, stream>>>(images, M[0], stem_w, stats);
  k_bnfinal<<<1, CH, 0, stream>>>(stats, cnts + 0, stem_g, stem_b, ssA);

  // masked-BN sequence helper (levels 1..4), bf16 in/out
  auto bn = [&](const bf16* x, int lvl, const float* g, const float* bb,
                int relu, const bf16* idn, bf16* outp){
    int HW = Hs[lvl]*Hs[lvl];
    int total = NB*CH*HW;
    k_zero<<<2, 256, 0, stream>>>(stats, 2*CH);
    int nch = (NB*HW)/65536; if(nch < 1) nch = 1;
    k_bnstats<<<dim3(CH, nch), 256, 0, stream>>>(x, M[lvl], stats, HW);
    k_bnfinal<<<1, CH, 0, stream>>>(stats, cnts + lvl, g, bb, ss);
    int blocks = (total + 255)/256;
    if(idn)          k_bnapply<1,1><<<blocks, 256, 0, stream>>>(x, M[lvl], ss, idn, outp, HW);
    else if(relu)    k_bnapply<1,0><<<blocks, 256, 0, stream>>>(x, M[lvl], ss, nullptr, outp, HW);
    else             k_bnapply<0,0><<<blocks, 256, 0, stream>>>(x, M[lvl], ss, nullptr, outp, HW);
  };

  // simple direct conv for every level
  auto conv = [&](const bf16* inp, const float* wsrc, int Ho, int stride,
                  bf16* outp, const u8* mk){
    k_repack<<<(CH*CH*9+255)/256, 256, 0, stream>>>(wsrc, Wt);
    int total = NB*CH*Ho*Ho;
    int blocks = (total + 255)/256;
    if(stride == 2) k_conv3d<2><<<blocks, 256, 0, stream>>>(inp, Wt, mk, outp, Ho, Ho);
    else            k_conv3d<1><<<blocks, 256, 0, stream>>>(inp, Wt, mk, outp, Ho, Ho);
  };

  // ---- 4 stages; rotation: A=S0 always, B alternates, C2 = last-conv scratch ----
  bf16* X = nullptr;
  const int WSZ = CH*CH*9;
  for(int i=0;i<4;i++){
    int Ho = Hs[i+1];
    const u8* mk = M[i+1];
    bf16* A = S0;
    bf16* B = (i % 2 == 0) ? S1 : S2;
    bf16* C2 = (i == 0) ? S2 : X;

    if(i == 0){
      k_repack<<<(CH*CH*9+255)/256, 256, 0, stream>>>(dw1, Wt);
      int total = NB*CH*16384;
      k_conv0d<<<(total+255)/256, 256, 0, stream>>>(images, stem_w, ssA, M[0], Wt, M[1], A);
    } else {
      conv(X, dw1 + (size_t)i*WSZ, Ho, 2, A, mk);
    }
    bn(A, i+1, dg1 + i*CH, db1 + i*CH, 1, nullptr, A);
    conv(A, dw2 + (size_t)i*WSZ, Ho, 1, B, mk);
    bn(B, i+1, dg2 + i*CH, db2 + i*CH, 0, nullptr, B);
    conv(B, rw1 + (size_t)i*WSZ, Ho, 1, A, mk);
    bn(A, i+1, rg1 + i*CH, rb1 + i*CH, 1, nullptr, A);
    conv(A, rw2 + (size_t)i*WSZ, Ho, 1, C2, mk);
    bn(C2, i+1, rg2 + i*CH, rb2 + i*CH, 1, B, B);  // relu(bn*m + idn) -> B
    X = B;
  }

  // ---- final 1x1 + BN + ReLU -> d_out (float32) ----
  k_final<<<(NB*CH*256 + 255)/256, 256, 0, stream>>>(X, final_w, M[4], S0);
  {
    k_zero<<<2, 256, 0, stream>>>(stats, 2*CH);
    k_bnstats<<<dim3(CH, 1), 256, 0, stream>>>(S0, M[4], stats, 256);
    k_bnfinal<<<1, CH, 0, stream>>>(stats, cnts + 4, final_g, final_b, ss);
    int total = NB*CH*256;
    k_bnapply_out<<<(total+255)/256, 256, 0, stream>>>(S0, M[4], ss, outF, 256);
  }

  // ---- tail: mask + ids_restore (float32) ----
  k_tail<<<16, 256, 0, stream>>>(maskI, outF);
}

// Round 6
// 13916.258 us; speedup vs baseline: 9.3407x; 9.3407x over previous
//
#include <hip/hip_runtime.h>
#include <hip/hip_bf16.h>

typedef __hip_bfloat16 bf16;
typedef unsigned short u16;
typedef unsigned char u8;

#define NB 8
#define CH 192

static __device__ __forceinline__ float bf2f(bf16 v){ return __bfloat162float(v); }
static __device__ __forceinline__ u16 f2bu(float f){
  union { bf16 h; u16 u; } cv; cv.h = __float2bfloat16(f); return cv.u;
}

// ---------------- utility kernels ----------------

__global__ void k_zero(float* p, int n){
  int i = blockIdx.x*blockDim.x + threadIdx.x;
  if(i < n) p[i] = 0.f;
}

__global__ void k_fill(float* p, int n, float v){
  int i = blockIdx.x*blockDim.x + threadIdx.x;
  if(i < n) p[i] = v;
}

// m0[b,256,256] = 1 - mask[b, (y/16)*16 + (x/16)]   (mask: int32 0/1)
__global__ void k_mask0(const int* __restrict__ mask, u8* __restrict__ m0){
  int i = blockIdx.x*blockDim.x + threadIdx.x;
  if(i >= NB*65536) return;
  int b = i >> 16; int p = i & 65535;
  int y = p >> 8, x = p & 255;
  int patch = (y >> 4)*16 + (x >> 4);
  m0[i] = (u8)(1 - mask[b*256 + patch]);
}

// 3x3 stride-2 pad-1 max-pool of mask
__global__ void k_maskdown(const u8* __restrict__ mi, u8* __restrict__ mo,
                           int Ho, int Wo, int Hi, int Wi){
  int i = blockIdx.x*blockDim.x + threadIdx.x;
  int total = NB*Ho*Wo; if(i >= total) return;
  int b = i/(Ho*Wo); int p = i%(Ho*Wo);
  int oy = p/Wo, ox = p%Wo;
  u8 v = 0;
  for(int ky=0; ky<3; ky++){
    int iy = oy*2 + ky - 1; if(iy < 0 || iy >= Hi) continue;
    for(int kx=0; kx<3; kx++){
      int ix = ox*2 + kx - 1; if(ix < 0 || ix >= Wi) continue;
      u8 t = mi[(b*Hi + iy)*Wi + ix]; if(t > v) v = t;
    }
  }
  mo[i] = v;
}

__global__ void k_count(const u8* __restrict__ m, int n, float* cnt){
  int i = blockIdx.x*blockDim.x + threadIdx.x;
  int stride = gridDim.x*blockDim.x;
  int local = 0;
  for(int j=i; j<n; j+=stride) local += m[j];
  for(int o=32; o>0; o>>=1) local += __shfl_down(local, o, 64);
  if((threadIdx.x & 63) == 0 && local) atomicAdd(cnt, (float)local);
}

// ---------------- stem BN stats: block = (channel, pixel-chunk), images f32 ----------------

__global__ __launch_bounds__(256) void k_stemstats2(const float* __restrict__ im,
        const u8* __restrict__ m0, const float* __restrict__ sw,
        float* __restrict__ stats){
  int c = blockIdx.x;          // 0..191
  int chunk = blockIdx.y;      // 0..127, 4096 px each (8*65536 total)
  float w0 = sw[c*3+0], w1 = sw[c*3+1], w2 = sw[c*3+2];
  float s = 0.f, s2 = 0.f;
  int start = chunk*4096;
  for(int j = start + threadIdx.x; j < start + 4096; j += 256){
    if(m0[j]){
      int b = j >> 16, p = j & 65535;
      float d = w0*im[(size_t)(b*3+0)*65536 + p]
              + w1*im[(size_t)(b*3+1)*65536 + p]
              + w2*im[(size_t)(b*3+2)*65536 + p];
      s += d; s2 += d*d;
    }
  }
  for(int o=32; o>0; o>>=1){ s += __shfl_down(s, o, 64); s2 += __shfl_down(s2, o, 64); }
  __shared__ float sh[8];
  int w = threadIdx.x >> 6;
  if((threadIdx.x & 63) == 0){ sh[w] = s; sh[4+w] = s2; }
  __syncthreads();
  if(threadIdx.x == 0){
    float ts = 0.f, t2 = 0.f;
    for(int k=0;k<4;k++){ ts += sh[k]; t2 += sh[4+k]; }
    atomicAdd(&stats[c], ts);
    atomicAdd(&stats[CH + c], t2);
  }
}

// ---------------- weight repack: W[co,ci,3,3] f32 -> Wt[(ci*192+co)*12 + k] f32 ----------------

__global__ void k_repack(const float* __restrict__ w, float* __restrict__ wt){
  int i = blockIdx.x*blockDim.x + threadIdx.x;
  if(i >= CH*CH*9) return;
  int k = i % 9; int ci = (i/9) % CH; int co = i/(9*CH);
  wt[(ci*CH + co)*12 + k] = w[i];
}

// ---------------- shared tile-compute for 3x3 convs (8x8 outputs/thread) ----------------

template<int S>
__device__ __forceinline__ void conv_tile_compute(const float* __restrict__ tile,
        const float* __restrict__ w, float* __restrict__ acc){
  constexpr int TH = (S==1) ? 10 : 17;
  constexpr int TW = TH;
  constexpr int ROWP = (S==1) ? 10 : 18;
  float rb_[3][18];
#pragma unroll
  for(int rr=0; rr<TH; rr++){
#pragma unroll
    for(int j=0; j<TW; j+=2){
      float2 v = *(const float2*)&tile[rr*ROWP + j];
      rb_[rr%3][j] = v.x; rb_[rr%3][j+1] = v.y;
    }
    if(rr >= 2 && ((rr-2) % S) == 0){
      const int r = (rr-2)/S;
#pragma unroll
      for(int ox=0; ox<8; ox++){
        float s0 = w[0]*rb_[(rr-2)%3][ox*S+0] + w[1]*rb_[(rr-2)%3][ox*S+1] + w[2]*rb_[(rr-2)%3][ox*S+2];
        float s1 = w[3]*rb_[(rr-1)%3][ox*S+0] + w[4]*rb_[(rr-1)%3][ox*S+1] + w[5]*rb_[(rr-1)%3][ox*S+2];
        float s2 = w[6]*rb_[(rr  )%3][ox*S+0] + w[7]*rb_[(rr  )%3][ox*S+1] + w[8]*rb_[(rr  )%3][ox*S+2];
        acc[r*8+ox] += s0 + s1 + s2;
      }
    }
  }
}

// common epilogue: write 8x8 x 192ch tile to global via LDS staging
__device__ __forceinline__ void conv_tile_store(float* __restrict__ acc, u16* __restrict__ obuf,
        bf16* __restrict__ out, int b, int oy0, int ox0, int Ho, int Wo, int t){
  __syncthreads();
#pragma unroll
  for(int p=0;p<64;p++) obuf[t*64 + p] = f2bu(acc[p]);
  __syncthreads();
  for(int c=t; c<CH*16; c+=192){
    int co = c >> 4; int rem = c & 15; int r = rem >> 1; int xh = (rem & 1)*4;
    ushort4 v = *(const ushort4*)&obuf[co*64 + r*8 + xh];
    *(ushort4*)((u16*)out + ((size_t)(b*CH + co)*Ho + oy0 + r)*Wo + ox0 + xh) = v;
  }
}

// ---------------- tiled 3x3 conv, 192 threads = 1 c_out each, 8x8 output tile ----------------

template<int S>
__global__ __launch_bounds__(192) void k_conv3t(const bf16* __restrict__ in,
        const float* __restrict__ wt, const u8* __restrict__ mk,
        bf16* __restrict__ out, int Ho, int Wo){
  constexpr int TH = (S==1) ? 10 : 17;
  constexpr int TW = TH;
  constexpr int ROWP = (S==1) ? 10 : 18;
  __shared__ __align__(16) float tile[17*18];
  __shared__ __align__(16) u16 obuf[CH*64];
  __shared__ int anyact;
  const int t = threadIdx.x;
  const int b = blockIdx.z;
  const int ox0 = blockIdx.x*8, oy0 = blockIdx.y*8;
  const int Hi = Ho*S, Wi = Wo*S;

  if(t == 0) anyact = 0;
  __syncthreads();
  if(t < 64){
    int r = t >> 3, c = t & 7;
    if(mk[(b*Ho + oy0 + r)*Wo + ox0 + c]) anyact = 1;
  }
  __syncthreads();
  if(!anyact) return;  // whole output tile inactive -> garbage masked by BN apply

  float acc[64];
#pragma unroll
  for(int i=0;i<64;i++) acc[i] = 0.f;
  const int gy0 = oy0*S - 1, gx0 = ox0*S - 1;

  for(int ci=0; ci<CH; ci++){
    __syncthreads();
    for(int e=t; e<TH*TW; e+=192){
      int r = e / TW, c = e % TW;
      int gy = gy0 + r, gx = gx0 + c;
      float v = 0.f;
      if(gy >= 0 && gy < Hi && gx >= 0 && gx < Wi)
        v = bf2f(in[((size_t)(b*CH + ci)*Hi + gy)*Wi + gx]);
      tile[r*ROWP + c] = v;
    }
    __syncthreads();
    float w[9];
#pragma unroll
    for(int k=0;k<9;k++) w[k] = wt[(ci*CH + t)*12 + k];
    conv_tile_compute<S>(tile, w, acc);
  }
  conv_tile_store(acc, obuf, out, b, oy0, ox0, Ho, Wo, t);
}

// ---------------- stage-0 fused conv: stem(1x1 f32)+BN+ReLU on the fly, then k3 s2 ----------------

__global__ __launch_bounds__(192) void k_conv0(const float* __restrict__ im,
        const float* __restrict__ sw, const float* __restrict__ ssA,
        const u8* __restrict__ m0, const float* __restrict__ wt,
        const u8* __restrict__ mk, bf16* __restrict__ out){
  __shared__ __align__(16) float tile[17*18];
  __shared__ float rgbs[3][292];
  __shared__ u8 mts[292];
  __shared__ __align__(16) u16 obuf[CH*64];
  __shared__ int anyact;
  const int t = threadIdx.x;
  const int b = blockIdx.z;
  const int ox0 = blockIdx.x*8, oy0 = blockIdx.y*8;

  if(t == 0) anyact = 0;
  __syncthreads();
  if(t < 64){
    int r = t >> 3, c = t & 7;
    if(mk[(b*128 + oy0 + r)*128 + ox0 + c]) anyact = 1;
  }
  __syncthreads();
  if(!anyact) return;

  const int gy0 = oy0*2 - 1, gx0 = ox0*2 - 1;
  for(int e=t; e<289; e+=192){
    int r = e/17, c = e%17;
    int gy = gy0 + r, gx = gx0 + c;
    float r_=0.f, g_=0.f, bl=0.f; u8 mv=0;
    if(gy >= 0 && gy < 256 && gx >= 0 && gx < 256){
      int pi = gy*256 + gx;
      mv = m0[b*65536 + pi];
      r_ = im[(size_t)(b*3+0)*65536 + pi];
      g_ = im[(size_t)(b*3+1)*65536 + pi];
      bl = im[(size_t)(b*3+2)*65536 + pi];
    }
    rgbs[0][e]=r_; rgbs[1][e]=g_; rgbs[2][e]=bl; mts[e]=mv;
  }

  float acc[64];
#pragma unroll
  for(int i=0;i<64;i++) acc[i] = 0.f;

  for(int ci=0; ci<CH; ci++){
    float w0 = sw[ci*3+0], w1 = sw[ci*3+1], w2 = sw[ci*3+2];
    float sc = ssA[ci], sh = ssA[CH+ci];
    __syncthreads();
    for(int e=t; e<289; e+=192){
      float d = w0*rgbs[0][e] + w1*rgbs[1][e] + w2*rgbs[2][e];
      float a = mts[e] ? fmaxf(sc*d + sh, 0.f) : 0.f;
      tile[(e/17)*18 + (e%17)] = a;
    }
    __syncthreads();
    float w[9];
#pragma unroll
    for(int k=0;k<9;k++) w[k] = wt[(ci*CH + t)*12 + k];
    conv_tile_compute<2>(tile, w, acc);
  }
  conv_tile_store(acc, obuf, out, b, oy0, ox0, 128, 128, t);
}

// ---------------- direct 3x3 conv (16x16 level only), thread per output ----------------

template<int S>
__global__ void k_conv3d(const bf16* __restrict__ in, const float* __restrict__ wt,
                         const u8* __restrict__ mk, bf16* __restrict__ out, int Ho, int Wo){
  int i = blockIdx.x*blockDim.x + threadIdx.x;
  int HW = Ho*Wo;
  int total = NB*CH*HW; if(i >= total) return;
  int p = i % HW; int co = (i/HW) % CH; int b = i/(HW*CH);
  if(!mk[b*HW + p]) return;  // inactive output, masked later
  int oy = p / Wo, ox = p % Wo;
  int Hi = Ho*S, Wi = Wo*S;
  int iy0 = oy*S - 1, ix0 = ox*S - 1;
  float acc = 0.f;
  for(int ci=0; ci<CH; ci++){
    const bf16* ib = in + (size_t)((b*CH + ci)*Hi)*Wi;
    float w[9];
#pragma unroll
    for(int k=0;k<9;k++) w[k] = wt[(ci*CH + co)*12 + k];
#pragma unroll
    for(int ky=0; ky<3; ky++){
      int iy = iy0 + ky; if(iy < 0 || iy >= Hi) continue;
#pragma unroll
      for(int kx=0; kx<3; kx++){
        int ix = ix0 + kx; if(ix < 0 || ix >= Wi) continue;
        acc += w[ky*3+kx]*bf2f(ib[iy*Wi + ix]);
      }
    }
  }
  out[i] = __float2bfloat16(acc);
}

// ---------------- masked BN: stats / finalize / apply ----------------

__global__ void k_bnstats(const bf16* __restrict__ x, const u8* __restrict__ m,
                          float* __restrict__ stats, int HW){
  int c = blockIdx.x;
  int nchunk = gridDim.y;
  int nper = (NB*HW + nchunk - 1)/nchunk;
  int start = blockIdx.y*nper;
  int end = start + nper; if(end > NB*HW) end = NB*HW;
  float s = 0.f, s2 = 0.f;
  for(int i = start + threadIdx.x; i < end; i += blockDim.x){
    int b = i / HW, p = i % HW;
    if(m[b*HW + p]){
      float v = bf2f(x[(size_t)(b*CH + c)*HW + p]);
      s += v; s2 += v*v;
    }
  }
  for(int o=32; o>0; o>>=1){ s += __shfl_down(s, o, 64); s2 += __shfl_down(s2, o, 64); }
  __shared__ float sh[8];
  int w = threadIdx.x >> 6;
  if((threadIdx.x & 63) == 0){ sh[w] = s; sh[4+w] = s2; }
  __syncthreads();
  if(threadIdx.x == 0){
    float ts = 0.f, t2 = 0.f;
    int nw = blockDim.x >> 6;
    for(int k=0;k<nw;k++){ ts += sh[k]; t2 += sh[4+k]; }
    atomicAdd(&stats[c], ts);
    atomicAdd(&stats[CH + c], t2);
  }
}

__global__ void k_bnfinal(const float* __restrict__ stats, const float* __restrict__ cnt,
                          const float* __restrict__ g, const float* __restrict__ bb,
                          float* __restrict__ ss){
  int c = threadIdx.x; if(c >= CH) return;
  float n = fmaxf(*cnt, 1.0f);
  float mean = stats[c]/n;
  float var = stats[CH + c]/n - mean*mean;
  var = fmaxf(var, 0.f);
  float rstd = rsqrtf(var + 1e-5f);
  float sc = g[c]*rstd;
  ss[c] = sc;
  ss[CH + c] = bb[c] - mean*sc;
}

template<int RELU, int ADD>
__global__ void k_bnapply(const bf16* __restrict__ x, const u8* __restrict__ m,
                          const float* __restrict__ ss, const bf16* __restrict__ idn,
                          bf16* __restrict__ out, int HW){
  int i = blockIdx.x*blockDim.x + threadIdx.x;
  int total = NB*CH*HW; if(i >= total) return;
  int p = i % HW; int c = (i/HW) % CH; int b = i/(HW*CH);
  float v = bf2f(x[i])*ss[c] + ss[CH + c];
  v *= (float)m[b*HW + p];
  if(ADD) v += bf2f(idn[i]);
  if(RELU) v = fmaxf(v, 0.f);
  out[i] = __float2bfloat16(v);
}

// final BN apply: relu, no add, float32 output (x region of d_out)
__global__ void k_bnapply_out(const bf16* __restrict__ x, const u8* __restrict__ m,
                              const float* __restrict__ ss, float* __restrict__ out, int HW){
  int i = blockIdx.x*blockDim.x + threadIdx.x;
  int total = NB*CH*HW; if(i >= total) return;
  int p = i % HW; int c = (i/HW) % CH; int b = i/(HW*CH);
  float v = bf2f(x[i])*ss[c] + ss[CH + c];
  v *= (float)m[b*HW + p];
  v = fmaxf(v, 0.f);
  out[i] = v;
}

// ---------------- final 1x1 conv (192 -> 192) at 16x16 ----------------

__global__ void k_final(const bf16* __restrict__ in, const float* __restrict__ w,
                        const u8* __restrict__ m4, bf16* __restrict__ out){
  int i = blockIdx.x*blockDim.x + threadIdx.x;
  if(i >= NB*CH*256) return;
  int p = i & 255; int co = (i >> 8) % CH; int b = i/(256*CH);
  if(!m4[b*256 + p]) return;
  float acc = 0.f;
  for(int ci=0; ci<CH; ci++)
    acc += w[co*CH + ci]*bf2f(in[(b*CH + ci)*256 + p]);
  out[i] = __float2bfloat16(acc);
}

// ---------------- tail: mask + ids_restore outputs (float32) ----------------

__global__ void k_tail(const int* __restrict__ mask, float* __restrict__ out){
  int i = blockIdx.x*blockDim.x + threadIdx.x;
  if(i < 2048){
    out[393216 + i] = (float)mask[i];
  } else if(i < 4096){
    int j = i - 2048;
    out[395264 + j] = (float)(j & 255);
  }
}

// ---------------- host orchestration ----------------

extern "C" void kernel_launch(void* const* d_in, const int* in_sizes, int n_in,
                              void* d_out, int out_size, void* d_ws, size_t ws_size,
                              hipStream_t stream){
  const float* images = (const float*)d_in[0];
  const int*   maskI  = (const int*)d_in[1];
  const float* stem_w = (const float*)d_in[2];
  const float* stem_g = (const float*)d_in[3];
  const float* stem_b = (const float*)d_in[4];
  const float* dw1 = (const float*)d_in[5];
  const float* dg1 = (const float*)d_in[6];
  const float* db1 = (const float*)d_in[7];
  const float* dw2 = (const float*)d_in[8];
  const float* dg2 = (const float*)d_in[9];
  const float* db2 = (const float*)d_in[10];
  const float* rw1 = (const float*)d_in[11];
  const float* rg1 = (const float*)d_in[12];
  const float* rb1 = (const float*)d_in[13];
  const float* rw2 = (const float*)d_in[14];
  const float* rg2 = (const float*)d_in[15];
  const float* rb2 = (const float*)d_in[16];
  const float* final_w = (const float*)d_in[17];
  const float* final_g = (const float*)d_in[18];
  const float* final_b = (const float*)d_in[19];
  float* outF = (float*)d_out;

  // workspace carve (~154 MB); activations stored bf16 internally
  char* wsp = (char*)d_ws;
  auto alloc = [&](size_t bytes)->char*{
    char* p = wsp; wsp += (bytes + 255) & ~(size_t)255; return p;
  };
  bf16* S0 = (bf16*)alloc((size_t)NB*CH*16384*2);
  bf16* S1 = (bf16*)alloc((size_t)NB*CH*16384*2);
  bf16* S2 = (bf16*)alloc((size_t)NB*CH*16384*2);
  int Hs[5] = {256,128,64,32,16};
  u8* M[5];
  for(int l=0;l<5;l++) M[l] = (u8*)alloc((size_t)NB*Hs[l]*Hs[l]);
  float* Wt = (float*)alloc((size_t)CH*CH*12*4);
  float* stats = (float*)alloc(2*CH*4);
  float* ss    = (float*)alloc(2*CH*4);
  float* ssA   = (float*)alloc(2*CH*4);
  float* cnts  = (float*)alloc(8*4);
  size_t need = (size_t)(wsp - (char*)d_ws);

  // fallback with DISTINCT signature (777): if absmax ~777 shows up,
  // workspace is too small — unambiguous vs any compute bug.
  if(ws_size < need){
    k_fill<<<(393216+255)/256, 256, 0, stream>>>(outF, 393216, 777.0f);
    k_tail<<<16, 256, 0, stream>>>(maskI, outF);
    return;
  }

  // ---- mask pyramid + counts ----
  k_mask0<<<(NB*65536+255)/256, 256, 0, stream>>>(maskI, M[0]);
  for(int l=1;l<5;l++){
    int total = NB*Hs[l]*Hs[l];
    k_maskdown<<<(total+255)/256, 256, 0, stream>>>(M[l-1], M[l], Hs[l], Hs[l], Hs[l-1], Hs[l-1]);
  }
  k_zero<<<1, 32, 0, stream>>>(cnts, 8);
  for(int l=0;l<5;l++){
    int n = NB*Hs[l]*Hs[l];
    int blocks = (n + 256*64 - 1)/(256*64); if(blocks < 1) blocks = 1; if(blocks > 256) blocks = 256;
    k_count<<<blocks, 256, 0, stream>>>(M[l], n, cnts + l);
  }

  // ---- stem BN params (stats computed on the fly, nothing materialized) ----
  k_zero<<<2, 256, 0, stream>>>(stats, 2*CH);
  k_stemstats2<<<dim3(CH, 128), 256, 0, stream>>>(images, M[0], stem_w, stats);
  k_bnfinal<<<1, CH, 0, stream>>>(stats, cnts + 0, stem_g, stem_b, ssA);

  // masked-BN sequence helper (levels 1..4), bf16 in/out
  auto bn = [&](const bf16* x, int lvl, const float* g, const float* bb,
                int relu, const bf16* idn, bf16* outp){
    int HW = Hs[lvl]*Hs[lvl];
    int total = NB*CH*HW;
    k_zero<<<2, 256, 0, stream>>>(stats, 2*CH);
    int nch = (NB*HW)/65536; if(nch < 1) nch = 1;
    k_bnstats<<<dim3(CH, nch), 256, 0, stream>>>(x, M[lvl], stats, HW);
    k_bnfinal<<<1, CH, 0, stream>>>(stats, cnts + lvl, g, bb, ss);
    int blocks = (total + 255)/256;
    if(idn)          k_bnapply<1,1><<<blocks, 256, 0, stream>>>(x, M[lvl], ss, idn, outp, HW);
    else if(relu)    k_bnapply<1,0><<<blocks, 256, 0, stream>>>(x, M[lvl], ss, nullptr, outp, HW);
    else             k_bnapply<0,0><<<blocks, 256, 0, stream>>>(x, M[lvl], ss, nullptr, outp, HW);
  };

  // conv: tiled for Ho>=32, direct for 16
  auto conv = [&](const bf16* inp, const float* wsrc, int Ho, int stride,
                  bf16* outp, const u8* mk){
    k_repack<<<(CH*CH*9+255)/256, 256, 0, stream>>>(wsrc, Wt);
    if(Ho >= 32){
      dim3 g(Ho/8, Ho/8, NB);
      if(stride == 2) k_conv3t<2><<<g, 192, 0, stream>>>(inp, Wt, mk, outp, Ho, Ho);
      else            k_conv3t<1><<<g, 192, 0, stream>>>(inp, Wt, mk, outp, Ho, Ho);
    } else {
      int total = NB*CH*Ho*Ho;
      int blocks = (total + 255)/256;
      if(stride == 2) k_conv3d<2><<<blocks, 256, 0, stream>>>(inp, Wt, mk, outp, Ho, Ho);
      else            k_conv3d<1><<<blocks, 256, 0, stream>>>(inp, Wt, mk, outp, Ho, Ho);
    }
  };

  // ---- 4 stages; rotation: A=S0 always, B alternates, C2 = last-conv scratch ----
  bf16* X = nullptr;
  const int WSZ = CH*CH*9;
  for(int i=0;i<4;i++){
    int Ho = Hs[i+1];
    const u8* mk = M[i+1];
    bf16* A = S0;
    bf16* B = (i % 2 == 0) ? S1 : S2;
    bf16* C2 = (i == 0) ? S2 : X;

    if(i == 0){
      k_repack<<<(CH*CH*9+255)/256, 256, 0, stream>>>(dw1, Wt);
      dim3 g(16, 16, NB);
      k_conv0<<<g, 192, 0, stream>>>(images, stem_w, ssA, M[0], Wt, M[1], A);
    } else {
      conv(X, dw1 + (size_t)i*WSZ, Ho, 2, A, mk);
    }
    bn(A, i+1, dg1 + i*CH, db1 + i*CH, 1, nullptr, A);
    conv(A, dw2 + (size_t)i*WSZ, Ho, 1, B, mk);
    bn(B, i+1, dg2 + i*CH, db2 + i*CH, 0, nullptr, B);
    conv(B, rw1 + (size_t)i*WSZ, Ho, 1, A, mk);
    bn(A, i+1, rg1 + i*CH, rb1 + i*CH, 1, nullptr, A);
    conv(A, rw2 + (size_t)i*WSZ, Ho, 1, C2, mk);
    bn(C2, i+1, rg2 + i*CH, rb2 + i*CH, 1, B, B);  // relu(bn*m + idn) -> B
    X = B;
  }

  // ---- final 1x1 + BN + ReLU -> d_out (float32) ----
  k_final<<<(NB*CH*256 + 255)/256, 256, 0, stream>>>(X, final_w, M[4], S0);
  {
    k_zero<<<2, 256, 0, stream>>>(stats, 2*CH);
    k_bnstats<<<dim3(CH, 1), 256, 0, stream>>>(S0, M[4], stats, 256);
    k_bnfinal<<<1, CH, 0, stream>>>(stats, cnts + 4, final_g, final_b, ss);
    int total = NB*CH*256;
    k_bnapply_out<<<(total+255)/256, 256, 0, stream>>>(S0, M[4], ss, outF, 256);
  }

  // ---- tail: mask + ids_restore (float32) ----
  k_tail<<<16, 256, 0, stream>>>(maskI, outF);
}

// Round 7
// 8134.383 us; speedup vs baseline: 15.9800x; 1.7108x over previous
//
#include <hip/hip_runtime.h>
#include <hip/hip_bf16.h>

typedef __hip_bfloat16 bf16;
typedef unsigned short u16;
typedef unsigned char u8;
typedef __attribute__((ext_vector_type(8))) short bf16x8;
typedef __attribute__((ext_vector_type(4))) float f32x4;

#define NB 8
#define CH 192

static __device__ __forceinline__ float bf2f(bf16 v){ return __bfloat162float(v); }
static __device__ __forceinline__ u16 f2bu(float f){
  union { bf16 h; u16 u; } cv; cv.h = __float2bfloat16(f); return cv.u;
}

// ---------------- utility kernels ----------------

__global__ void k_zero(float* p, int n){
  int i = blockIdx.x*blockDim.x + threadIdx.x;
  if(i < n) p[i] = 0.f;
}

__global__ void k_fill(float* p, int n, float v){
  int i = blockIdx.x*blockDim.x + threadIdx.x;
  if(i < n) p[i] = v;
}

// m0[b,256,256] = 1 - mask[b, (y/16)*16 + (x/16)]   (mask: int32 0/1)
__global__ void k_mask0(const int* __restrict__ mask, u8* __restrict__ m0){
  int i = blockIdx.x*blockDim.x + threadIdx.x;
  if(i >= NB*65536) return;
  int b = i >> 16; int p = i & 65535;
  int y = p >> 8, x = p & 255;
  int patch = (y >> 4)*16 + (x >> 4);
  m0[i] = (u8)(1 - mask[b*256 + patch]);
}

// 3x3 stride-2 pad-1 max-pool of mask
__global__ void k_maskdown(const u8* __restrict__ mi, u8* __restrict__ mo,
                           int Ho, int Wo, int Hi, int Wi){
  int i = blockIdx.x*blockDim.x + threadIdx.x;
  int total = NB*Ho*Wo; if(i >= total) return;
  int b = i/(Ho*Wo); int p = i%(Ho*Wo);
  int oy = p/Wo, ox = p%Wo;
  u8 v = 0;
  for(int ky=0; ky<3; ky++){
    int iy = oy*2 + ky - 1; if(iy < 0 || iy >= Hi) continue;
    for(int kx=0; kx<3; kx++){
      int ix = ox*2 + kx - 1; if(ix < 0 || ix >= Wi) continue;
      u8 t = mi[(b*Hi + iy)*Wi + ix]; if(t > v) v = t;
    }
  }
  mo[i] = v;
}

__global__ void k_count(const u8* __restrict__ m, int n, float* cnt){
  int i = blockIdx.x*blockDim.x + threadIdx.x;
  int stride = gridDim.x*blockDim.x;
  int local = 0;
  for(int j=i; j<n; j+=stride) local += m[j];
  for(int o=32; o>0; o>>=1) local += __shfl_down(local, o, 64);
  if((threadIdx.x & 63) == 0 && local) atomicAdd(cnt, (float)local);
}

// ---------------- stem BN stats: block = (channel, pixel-chunk), images f32 ----------------

__global__ __launch_bounds__(256) void k_stemstats2(const float* __restrict__ im,
        const u8* __restrict__ m0, const float* __restrict__ sw,
        float* __restrict__ stats){
  int c = blockIdx.x;          // 0..191
  int chunk = blockIdx.y;      // 0..127, 4096 px each (8*65536 total)
  float w0 = sw[c*3+0], w1 = sw[c*3+1], w2 = sw[c*3+2];
  float s = 0.f, s2 = 0.f;
  int start = chunk*4096;
  for(int j = start + threadIdx.x; j < start + 4096; j += 256){
    if(m0[j]){
      int b = j >> 16, p = j & 65535;
      float d = w0*im[(size_t)(b*3+0)*65536 + p]
              + w1*im[(size_t)(b*3+1)*65536 + p]
              + w2*im[(size_t)(b*3+2)*65536 + p];
      s += d; s2 += d*d;
    }
  }
  for(int o=32; o>0; o>>=1){ s += __shfl_down(s, o, 64); s2 += __shfl_down(s2, o, 64); }
  __shared__ float sh[8];
  int w = threadIdx.x >> 6;
  if((threadIdx.x & 63) == 0){ sh[w] = s; sh[4+w] = s2; }
  __syncthreads();
  if(threadIdx.x == 0){
    float ts = 0.f, t2 = 0.f;
    for(int k=0;k<4;k++){ ts += sh[k]; t2 += sh[4+k]; }
    atomicAdd(&stats[c], ts);
    atomicAdd(&stats[CH + c], t2);
  }
}

// ---------------- weight repacks ----------------
// f32: W[co,ci,3,3] -> Wt[(ci*192+co)*12 + k]   (for VALU convs)
__global__ void k_repack(const float* __restrict__ w, float* __restrict__ wt){
  int i = blockIdx.x*blockDim.x + threadIdx.x;
  if(i >= CH*CH*9) return;
  int k = i % 9; int ci = (i/9) % CH; int co = i/(9*CH);
  wt[(ci*CH + co)*12 + k] = w[i];
}
// bf16: W[co,ci,3,3] -> Wb[tap][co][ci]   (B^T layout for MFMA, k=ci contiguous)
__global__ void k_repackb(const float* __restrict__ w, bf16* __restrict__ wb){
  int i = blockIdx.x*blockDim.x + threadIdx.x;
  if(i >= CH*CH*9) return;
  int tap = i % 9; int ci = (i/9) % CH; int co = i/(9*CH);
  wb[(size_t)tap*CH*CH + co*CH + ci] = __float2bfloat16(w[i]);
}

// ---------------- MFMA implicit-GEMM 3x3 stride-1 conv ----------------
// block: 256 thr (4 waves), one 8x8 output tile, all 192 co.
// GEMM M=64 sites, N=192 co, K=9 taps x 192 ci (chunks of 32).
// LDS input tile [y][x][ci] 10x10x200(pad) bf16; A-frag = ds_read_b128.
#define CIP 200
__global__ __launch_bounds__(256) void k_convm(const bf16* __restrict__ in,
        const bf16* __restrict__ wb, const u8* __restrict__ mk,
        bf16* __restrict__ out, int Ho, int Wo){
  __shared__ __align__(16) u16 tile[10*10*CIP];   // 40000 B; obuf aliased after compute
  __shared__ int anyact;
  const int t = threadIdx.x;
  const int b = blockIdx.z;
  const int ox0 = blockIdx.x*8, oy0 = blockIdx.y*8;

  if(t == 0) anyact = 0;
  __syncthreads();
  if(t < 64){
    int r = t >> 3, c = t & 7;
    if(mk[(b*Ho + oy0 + r)*Wo + ox0 + c]) anyact = 1;
  }
  __syncthreads();
  if(!anyact) return;   // inactive tile: garbage masked by BN apply

  // ---- stage 10x10x192 input window once: [y][x][ci], zeros at borders ----
  const int gy0 = oy0 - 1, gx0 = ox0 - 1;
  for(int rr = t; rr < CH*10; rr += 256){
    int ci = rr/10, y = rr%10;
    int gy = gy0 + y;
    const u16* ib = (const u16*)(in + ((size_t)(b*CH + ci)*Ho + gy)*Wo);
    u16* ld = &tile[(y*10)*CIP + ci];
    bool rowok = (gy >= 0 && gy < Ho);
#pragma unroll
    for(int x=0; x<10; x++){
      int gx = gx0 + x;
      u16 v = 0;
      if(rowok && gx >= 0 && gx < Wo) v = ib[gx];
      ld[x*CIP] = v;
    }
  }
  __syncthreads();

  const int w = t >> 6;            // wave 0..3 -> co range [w*48, w*48+48)
  const int l = t & 63;
  const int l15 = l & 15, q = l >> 4;
  f32x4 acc[4][3];
#pragma unroll
  for(int mt=0;mt<4;mt++)
#pragma unroll
    for(int nt=0;nt<3;nt++) acc[mt][nt] = (f32x4){0.f,0.f,0.f,0.f};

  int sy[4], sx[4];
#pragma unroll
  for(int mt=0;mt<4;mt++){ int s = mt*16 + l15; sy[mt] = s>>3; sx[mt] = s&7; }
  const int co0 = w*48;

  for(int tap=0; tap<9; tap++){
    const int ky = tap/3, kx = tap%3;
    const u16* tb[4];
#pragma unroll
    for(int mt=0;mt<4;mt++)
      tb[mt] = &tile[((sy[mt]+ky)*10 + sx[mt]+kx)*CIP + q*8];
    const u16* wt0 = (const u16*)(wb + (size_t)tap*CH*CH);
#pragma unroll
    for(int c=0;c<6;c++){
      bf16x8 a[4], bb[3];
#pragma unroll
      for(int mt=0;mt<4;mt++) a[mt] = *(const bf16x8*)(tb[mt] + c*32);
#pragma unroll
      for(int nt=0;nt<3;nt++){
        int co = co0 + nt*16 + l15;
        bb[nt] = *(const bf16x8*)(wt0 + co*CH + c*32 + q*8);
      }
#pragma unroll
      for(int mt=0;mt<4;mt++)
#pragma unroll
        for(int nt=0;nt<3;nt++)
          acc[mt][nt] = __builtin_amdgcn_mfma_f32_16x16x32_bf16(a[mt], bb[nt], acc[mt][nt], 0, 0, 0);
    }
  }

  // ---- epilogue: C layout row=(lane>>4)*4+reg (site), col=lane&15 (co) ----
  __syncthreads();
  u16* obuf = tile;   // alias (needs 192*68 = 13056 u16 <= 20000)
#pragma unroll
  for(int mt=0;mt<4;mt++){
#pragma unroll
    for(int nt=0;nt<3;nt++){
      int co = co0 + nt*16 + l15;
#pragma unroll
      for(int r=0;r<4;r++){
        int site = mt*16 + q*4 + r;
        obuf[co*68 + site] = f2bu(acc[mt][nt][r]);
      }
    }
  }
  __syncthreads();
  for(int c=t; c<CH*16; c+=256){
    int co = c >> 4; int rem = c & 15; int r = rem >> 1; int xh = (rem & 1)*4;
    ushort4 v = *(const ushort4*)&obuf[co*68 + r*8 + xh];
    *(ushort4*)((u16*)out + ((size_t)(b*CH + co)*Ho + oy0 + r)*Wo + ox0 + xh) = v;
  }
}

// ---------------- shared tile-compute for VALU convs (8x8 outputs/thread) ----------------

template<int S>
__device__ __forceinline__ void conv_tile_compute(const float* __restrict__ tile,
        const float* __restrict__ w, float* __restrict__ acc){
  constexpr int TH = (S==1) ? 10 : 17;
  constexpr int TW = TH;
  constexpr int ROWP = (S==1) ? 10 : 18;
  float rb_[3][18];
#pragma unroll
  for(int rr=0; rr<TH; rr++){
#pragma unroll
    for(int j=0; j<TW; j+=2){
      float2 v = *(const float2*)&tile[rr*ROWP + j];
      rb_[rr%3][j] = v.x; rb_[rr%3][j+1] = v.y;
    }
    if(rr >= 2 && ((rr-2) % S) == 0){
      const int r = (rr-2)/S;
#pragma unroll
      for(int ox=0; ox<8; ox++){
        float s0 = w[0]*rb_[(rr-2)%3][ox*S+0] + w[1]*rb_[(rr-2)%3][ox*S+1] + w[2]*rb_[(rr-2)%3][ox*S+2];
        float s1 = w[3]*rb_[(rr-1)%3][ox*S+0] + w[4]*rb_[(rr-1)%3][ox*S+1] + w[5]*rb_[(rr-1)%3][ox*S+2];
        float s2 = w[6]*rb_[(rr  )%3][ox*S+0] + w[7]*rb_[(rr  )%3][ox*S+1] + w[8]*rb_[(rr  )%3][ox*S+2];
        acc[r*8+ox] += s0 + s1 + s2;
      }
    }
  }
}

// epilogue: 8x8 x 192ch tile via LDS staging; obuf stride 68 (2-way banks, 8B aligned)
__device__ __forceinline__ void conv_tile_store(float* __restrict__ acc, u16* __restrict__ obuf,
        bf16* __restrict__ out, int b, int oy0, int ox0, int Ho, int Wo, int t){
  __syncthreads();
#pragma unroll
  for(int p=0;p<64;p++) obuf[t*68 + p] = f2bu(acc[p]);
  __syncthreads();
  for(int c=t; c<CH*16; c+=192){
    int co = c >> 4; int rem = c & 15; int r = rem >> 1; int xh = (rem & 1)*4;
    ushort4 v = *(const ushort4*)&obuf[co*68 + r*8 + xh];
    *(ushort4*)((u16*)out + ((size_t)(b*CH + co)*Ho + oy0 + r)*Wo + ox0 + xh) = v;
  }
}

// ---------------- tiled 3x3 stride-2 conv (VALU), 192 thr = 1 c_out, 8x8 tile ----------------

template<int S>
__global__ __launch_bounds__(192) void k_conv3t(const bf16* __restrict__ in,
        const float* __restrict__ wt, const u8* __restrict__ mk,
        bf16* __restrict__ out, int Ho, int Wo){
  constexpr int TH = (S==1) ? 10 : 17;
  constexpr int TW = TH;
  constexpr int ROWP = (S==1) ? 10 : 18;
  __shared__ __align__(16) float tile[17*18];
  __shared__ __align__(16) u16 obuf[CH*68];
  __shared__ int anyact;
  const int t = threadIdx.x;
  const int b = blockIdx.z;
  const int ox0 = blockIdx.x*8, oy0 = blockIdx.y*8;
  const int Hi = Ho*S, Wi = Wo*S;

  if(t == 0) anyact = 0;
  __syncthreads();
  if(t < 64){
    int r = t >> 3, c = t & 7;
    if(mk[(b*Ho + oy0 + r)*Wo + ox0 + c]) anyact = 1;
  }
  __syncthreads();
  if(!anyact) return;

  float acc[64];
#pragma unroll
  for(int i=0;i<64;i++) acc[i] = 0.f;
  const int gy0 = oy0*S - 1, gx0 = ox0*S - 1;

  for(int ci=0; ci<CH; ci++){
    __syncthreads();
    for(int e=t; e<TH*TW; e+=192){
      int r = e / TW, c = e % TW;
      int gy = gy0 + r, gx = gx0 + c;
      float v = 0.f;
      if(gy >= 0 && gy < Hi && gx >= 0 && gx < Wi)
        v = bf2f(in[((size_t)(b*CH + ci)*Hi + gy)*Wi + gx]);
      tile[r*ROWP + c] = v;
    }
    __syncthreads();
    float w[9];
#pragma unroll
    for(int k=0;k<9;k++) w[k] = wt[(ci*CH + t)*12 + k];
    conv_tile_compute<S>(tile, w, acc);
  }
  conv_tile_store(acc, obuf, out, b, oy0, ox0, Ho, Wo, t);
}

// ---------------- stage-0 fused conv: stem(1x1 f32)+BN+ReLU on the fly, then k3 s2 ----------------

__global__ __launch_bounds__(192) void k_conv0(const float* __restrict__ im,
        const float* __restrict__ sw, const float* __restrict__ ssA,
        const u8* __restrict__ m0, const float* __restrict__ wt,
        const u8* __restrict__ mk, bf16* __restrict__ out){
  __shared__ __align__(16) float tile[17*18];
  __shared__ float rgbs[3][292];
  __shared__ u8 mts[292];
  __shared__ __align__(16) u16 obuf[CH*68];
  __shared__ int anyact;
  const int t = threadIdx.x;
  const int b = blockIdx.z;
  const int ox0 = blockIdx.x*8, oy0 = blockIdx.y*8;

  if(t == 0) anyact = 0;
  __syncthreads();
  if(t < 64){
    int r = t >> 3, c = t & 7;
    if(mk[(b*128 + oy0 + r)*128 + ox0 + c]) anyact = 1;
  }
  __syncthreads();
  if(!anyact) return;

  const int gy0 = oy0*2 - 1, gx0 = ox0*2 - 1;
  for(int e=t; e<289; e+=192){
    int r = e/17, c = e%17;
    int gy = gy0 + r, gx = gx0 + c;
    float r_=0.f, g_=0.f, bl=0.f; u8 mv=0;
    if(gy >= 0 && gy < 256 && gx >= 0 && gx < 256){
      int pi = gy*256 + gx;
      mv = m0[b*65536 + pi];
      r_ = im[(size_t)(b*3+0)*65536 + pi];
      g_ = im[(size_t)(b*3+1)*65536 + pi];
      bl = im[(size_t)(b*3+2)*65536 + pi];
    }
    rgbs[0][e]=r_; rgbs[1][e]=g_; rgbs[2][e]=bl; mts[e]=mv;
  }

  float acc[64];
#pragma unroll
  for(int i=0;i<64;i++) acc[i] = 0.f;

  for(int ci=0; ci<CH; ci++){
    float w0 = sw[ci*3+0], w1 = sw[ci*3+1], w2 = sw[ci*3+2];
    float sc = ssA[ci], sh = ssA[CH+ci];
    __syncthreads();
    for(int e=t; e<289; e+=192){
      float d = w0*rgbs[0][e] + w1*rgbs[1][e] + w2*rgbs[2][e];
      float a = mts[e] ? fmaxf(sc*d + sh, 0.f) : 0.f;
      tile[(e/17)*18 + (e%17)] = a;
    }
    __syncthreads();
    float w[9];
#pragma unroll
    for(int k=0;k<9;k++) w[k] = wt[(ci*CH + t)*12 + k];
    conv_tile_compute<2>(tile, w, acc);
  }
  conv_tile_store(acc, obuf, out, b, oy0, ox0, 128, 128, t);
}

// ---------------- direct 3x3 conv (16x16 level only), thread per output ----------------

template<int S>
__global__ void k_conv3d(const bf16* __restrict__ in, const float* __restrict__ wt,
                         const u8* __restrict__ mk, bf16* __restrict__ out, int Ho, int Wo){
  int i = blockIdx.x*blockDim.x + threadIdx.x;
  int HW = Ho*Wo;
  int total = NB*CH*HW; if(i >= total) return;
  int p = i % HW; int co = (i/HW) % CH; int b = i/(HW*CH);
  if(!mk[b*HW + p]) return;
  int oy = p / Wo, ox = p % Wo;
  int Hi = Ho*S, Wi = Wo*S;
  int iy0 = oy*S - 1, ix0 = ox*S - 1;
  float acc = 0.f;
  for(int ci=0; ci<CH; ci++){
    const bf16* ib = in + (size_t)((b*CH + ci)*Hi)*Wi;
    float w[9];
#pragma unroll
    for(int k=0;k<9;k++) w[k] = wt[(ci*CH + co)*12 + k];
#pragma unroll
    for(int ky=0; ky<3; ky++){
      int iy = iy0 + ky; if(iy < 0 || iy >= Hi) continue;
#pragma unroll
      for(int kx=0; kx<3; kx++){
        int ix = ix0 + kx; if(ix < 0 || ix >= Wi) continue;
        acc += w[ky*3+kx]*bf2f(ib[iy*Wi + ix]);
      }
    }
  }
  out[i] = __float2bfloat16(acc);
}

// ---------------- masked BN: stats / finalize / apply ----------------

__global__ void k_bnstats(const bf16* __restrict__ x, const u8* __restrict__ m,
                          float* __restrict__ stats, int HW){
  int c = blockIdx.x;
  int nchunk = gridDim.y;
  int nper = (NB*HW + nchunk - 1)/nchunk;
  int start = blockIdx.y*nper;
  int end = start + nper; if(end > NB*HW) end = NB*HW;
  float s = 0.f, s2 = 0.f;
  for(int i = start + threadIdx.x; i < end; i += blockDim.x){
    int b = i / HW, p = i % HW;
    if(m[b*HW + p]){
      float v = bf2f(x[(size_t)(b*CH + c)*HW + p]);
      s += v; s2 += v*v;
    }
  }
  for(int o=32; o>0; o>>=1){ s += __shfl_down(s, o, 64); s2 += __shfl_down(s2, o, 64); }
  __shared__ float sh[8];
  int w = threadIdx.x >> 6;
  if((threadIdx.x & 63) == 0){ sh[w] = s; sh[4+w] = s2; }
  __syncthreads();
  if(threadIdx.x == 0){
    float ts = 0.f, t2 = 0.f;
    int nw = blockDim.x >> 6;
    for(int k=0;k<nw;k++){ ts += sh[k]; t2 += sh[4+k]; }
    atomicAdd(&stats[c], ts);
    atomicAdd(&stats[CH + c], t2);
  }
}

__global__ void k_bnfinal(const float* __restrict__ stats, const float* __restrict__ cnt,
                          const float* __restrict__ g, const float* __restrict__ bb,
                          float* __restrict__ ss){
  int c = threadIdx.x; if(c >= CH) return;
  float n = fmaxf(*cnt, 1.0f);
  float mean = stats[c]/n;
  float var = stats[CH + c]/n - mean*mean;
  var = fmaxf(var, 0.f);
  float rstd = rsqrtf(var + 1e-5f);
  float sc = g[c]*rstd;
  ss[c] = sc;
  ss[CH + c] = bb[c] - mean*sc;
}

template<int RELU, int ADD>
__global__ void k_bnapply(const bf16* __restrict__ x, const u8* __restrict__ m,
                          const float* __restrict__ ss, const bf16* __restrict__ idn,
                          bf16* __restrict__ out, int HW){
  int i = blockIdx.x*blockDim.x + threadIdx.x;
  int total = NB*CH*HW; if(i >= total) return;
  int p = i % HW; int c = (i/HW) % CH; int b = i/(HW*CH);
  float v = bf2f(x[i])*ss[c] + ss[CH + c];
  v *= (float)m[b*HW + p];
  if(ADD) v += bf2f(idn[i]);
  if(RELU) v = fmaxf(v, 0.f);
  out[i] = __float2bfloat16(v);
}

// final BN apply: relu, no add, float32 output (x region of d_out)
__global__ void k_bnapply_out(const bf16* __restrict__ x, const u8* __restrict__ m,
                              const float* __restrict__ ss, float* __restrict__ out, int HW){
  int i = blockIdx.x*blockDim.x + threadIdx.x;
  int total = NB*CH*HW; if(i >= total) return;
  int p = i % HW; int c = (i/HW) % CH; int b = i/(HW*CH);
  float v = bf2f(x[i])*ss[c] + ss[CH + c];
  v *= (float)m[b*HW + p];
  v = fmaxf(v, 0.f);
  out[i] = v;
}

// ---------------- final 1x1 conv (192 -> 192) at 16x16 ----------------

__global__ void k_final(const bf16* __restrict__ in, const float* __restrict__ w,
                        const u8* __restrict__ m4, bf16* __restrict__ out){
  int i = blockIdx.x*blockDim.x + threadIdx.x;
  if(i >= NB*CH*256) return;
  int p = i & 255; int co = (i >> 8) % CH; int b = i/(256*CH);
  if(!m4[b*256 + p]) return;
  float acc = 0.f;
  for(int ci=0; ci<CH; ci++)
    acc += w[co*CH + ci]*bf2f(in[(b*CH + ci)*256 + p]);
  out[i] = __float2bfloat16(acc);
}

// ---------------- tail: mask + ids_restore outputs (float32) ----------------

__global__ void k_tail(const int* __restrict__ mask, float* __restrict__ out){
  int i = blockIdx.x*blockDim.x + threadIdx.x;
  if(i < 2048){
    out[393216 + i] = (float)mask[i];
  } else if(i < 4096){
    int j = i - 2048;
    out[395264 + j] = (float)(j & 255);
  }
}

// ---------------- host orchestration ----------------

extern "C" void kernel_launch(void* const* d_in, const int* in_sizes, int n_in,
                              void* d_out, int out_size, void* d_ws, size_t ws_size,
                              hipStream_t stream){
  const float* images = (const float*)d_in[0];
  const int*   maskI  = (const int*)d_in[1];
  const float* stem_w = (const float*)d_in[2];
  const float* stem_g = (const float*)d_in[3];
  const float* stem_b = (const float*)d_in[4];
  const float* dw1 = (const float*)d_in[5];
  const float* dg1 = (const float*)d_in[6];
  const float* db1 = (const float*)d_in[7];
  const float* dw2 = (const float*)d_in[8];
  const float* dg2 = (const float*)d_in[9];
  const float* db2 = (const float*)d_in[10];
  const float* rw1 = (const float*)d_in[11];
  const float* rg1 = (const float*)d_in[12];
  const float* rb1 = (const float*)d_in[13];
  const float* rw2 = (const float*)d_in[14];
  const float* rg2 = (const float*)d_in[15];
  const float* rb2 = (const float*)d_in[16];
  const float* final_w = (const float*)d_in[17];
  const float* final_g = (const float*)d_in[18];
  const float* final_b = (const float*)d_in[19];
  float* outF = (float*)d_out;

  // workspace carve (~156 MB); activations stored bf16 internally
  char* wsp = (char*)d_ws;
  auto alloc = [&](size_t bytes)->char*{
    char* p = wsp; wsp += (bytes + 255) & ~(size_t)255; return p;
  };
  bf16* S0 = (bf16*)alloc((size_t)NB*CH*16384*2);
  bf16* S1 = (bf16*)alloc((size_t)NB*CH*16384*2);
  bf16* S2 = (bf16*)alloc((size_t)NB*CH*16384*2);
  int Hs[5] = {256,128,64,32,16};
  u8* M[5];
  for(int l=0;l<5;l++) M[l] = (u8*)alloc((size_t)NB*Hs[l]*Hs[l]);
  float* Wt  = (float*)alloc((size_t)CH*CH*12*4);
  bf16*  Wb  = (bf16*)alloc((size_t)CH*CH*9*2);
  float* stats = (float*)alloc(2*CH*4);
  float* ss    = (float*)alloc(2*CH*4);
  float* ssA   = (float*)alloc(2*CH*4);
  float* cnts  = (float*)alloc(8*4);
  size_t need = (size_t)(wsp - (char*)d_ws);

  if(ws_size < need){
    k_fill<<<(393216+255)/256, 256, 0, stream>>>(outF, 393216, 777.0f);
    k_tail<<<16, 256, 0, stream>>>(maskI, outF);
    return;
  }

  // ---- mask pyramid + counts ----
  k_mask0<<<(NB*65536+255)/256, 256, 0, stream>>>(maskI, M[0]);
  for(int l=1;l<5;l++){
    int total = NB*Hs[l]*Hs[l];
    k_maskdown<<<(total+255)/256, 256, 0, stream>>>(M[l-1], M[l], Hs[l], Hs[l], Hs[l-1], Hs[l-1]);
  }
  k_zero<<<1, 32, 0, stream>>>(cnts, 8);
  for(int l=0;l<5;l++){
    int n = NB*Hs[l]*Hs[l];
    int blocks = (n + 256*64 - 1)/(256*64); if(blocks < 1) blocks = 1; if(blocks > 256) blocks = 256;
    k_count<<<blocks, 256, 0, stream>>>(M[l], n, cnts + l);
  }

  // ---- stem BN params ----
  k_zero<<<2, 256, 0, stream>>>(stats, 2*CH);
  k_stemstats2<<<dim3(CH, 128), 256, 0, stream>>>(images, M[0], stem_w, stats);
  k_bnfinal<<<1, CH, 0, stream>>>(stats, cnts + 0, stem_g, stem_b, ssA);

  // masked-BN sequence helper (levels 1..4), bf16 in/out
  auto bn = [&](const bf16* x, int lvl, const float* g, const float* bb,
                int relu, const bf16* idn, bf16* outp){
    int HW = Hs[lvl]*Hs[lvl];
    int total = NB*CH*HW;
    k_zero<<<2, 256, 0, stream>>>(stats, 2*CH);
    int nch = (NB*HW)/65536; if(nch < 1) nch = 1;
    k_bnstats<<<dim3(CH, nch), 256, 0, stream>>>(x, M[lvl], stats, HW);
    k_bnfinal<<<1, CH, 0, stream>>>(stats, cnts + lvl, g, bb, ss);
    int blocks = (total + 255)/256;
    if(idn)          k_bnapply<1,1><<<blocks, 256, 0, stream>>>(x, M[lvl], ss, idn, outp, HW);
    else if(relu)    k_bnapply<1,0><<<blocks, 256, 0, stream>>>(x, M[lvl], ss, nullptr, outp, HW);
    else             k_bnapply<0,0><<<blocks, 256, 0, stream>>>(x, M[lvl], ss, nullptr, outp, HW);
  };

  // conv router: s1 & Ho>=32 -> MFMA; s2 & Ho>=32 -> VALU tiled; Ho==16 -> direct
  auto conv = [&](const bf16* inp, const float* wsrc, int Ho, int stride,
                  bf16* outp, const u8* mk){
    if(stride == 1 && Ho >= 32){
      k_repackb<<<(CH*CH*9+255)/256, 256, 0, stream>>>(wsrc, Wb);
      dim3 g(Ho/8, Ho/8, NB);
      k_convm<<<g, 256, 0, stream>>>(inp, Wb, mk, outp, Ho, Ho);
    } else if(Ho >= 32){
      k_repack<<<(CH*CH*9+255)/256, 256, 0, stream>>>(wsrc, Wt);
      dim3 g(Ho/8, Ho/8, NB);
      k_conv3t<2><<<g, 192, 0, stream>>>(inp, Wt, mk, outp, Ho, Ho);
    } else {
      k_repack<<<(CH*CH*9+255)/256, 256, 0, stream>>>(wsrc, Wt);
      int total = NB*CH*Ho*Ho;
      int blocks = (total + 255)/256;
      if(stride == 2) k_conv3d<2><<<blocks, 256, 0, stream>>>(inp, Wt, mk, outp, Ho, Ho);
      else            k_conv3d<1><<<blocks, 256, 0, stream>>>(inp, Wt, mk, outp, Ho, Ho);
    }
  };

  // ---- 4 stages; rotation: A=S0 always, B alternates, C2 = last-conv scratch ----
  bf16* X = nullptr;
  const int WSZ = CH*CH*9;
  for(int i=0;i<4;i++){
    int Ho = Hs[i+1];
    const u8* mk = M[i+1];
    bf16* A = S0;
    bf16* B = (i % 2 == 0) ? S1 : S2;
    bf16* C2 = (i == 0) ? S2 : X;

    if(i == 0){
      k_repack<<<(CH*CH*9+255)/256, 256, 0, stream>>>(dw1, Wt);
      dim3 g(16, 16, NB);
      k_conv0<<<g, 192, 0, stream>>>(images, stem_w, ssA, M[0], Wt, M[1], A);
    } else {
      conv(X, dw1 + (size_t)i*WSZ, Ho, 2, A, mk);
    }
    bn(A, i+1, dg1 + i*CH, db1 + i*CH, 1, nullptr, A);
    conv(A, dw2 + (size_t)i*WSZ, Ho, 1, B, mk);
    bn(B, i+1, dg2 + i*CH, db2 + i*CH, 0, nullptr, B);
    conv(B, rw1 + (size_t)i*WSZ, Ho, 1, A, mk);
    bn(A, i+1, rg1 + i*CH, rb1 + i*CH, 1, nullptr, A);
    conv(A, rw2 + (size_t)i*WSZ, Ho, 1, C2, mk);
    bn(C2, i+1, rg2 + i*CH, rb2 + i*CH, 1, B, B);  // relu(bn*m + idn) -> B
    X = B;
  }

  // ---- final 1x1 + BN + ReLU -> d_out (float32) ----
  k_final<<<(NB*CH*256 + 255)/256, 256, 0, stream>>>(X, final_w, M[4], S0);
  {
    k_zero<<<2, 256, 0, stream>>>(stats, 2*CH);
    k_bnstats<<<dim3(CH, 1), 256, 0, stream>>>(S0, M[4], stats, 256);
    k_bnfinal<<<1, CH, 0, stream>>>(stats, cnts + 4, final_g, final_b, ss);
    int total = NB*CH*256;
    k_bnapply_out<<<(total+255)/256, 256, 0, stream>>>(S0, M[4], ss, outF, 256);
  }

  // ---- tail: mask + ids_restore (float32) ----
  k_tail<<<16, 256, 0, stream>>>(maskI, outF);
}

// Round 8
// 3682.314 us; speedup vs baseline: 35.3004x; 2.2090x over previous
//
#include <hip/hip_runtime.h>
#include <hip/hip_bf16.h>

typedef __hip_bfloat16 bf16;
typedef unsigned short u16;
typedef unsigned char u8;
typedef __attribute__((ext_vector_type(8))) short bf16x8;
typedef __attribute__((ext_vector_type(4))) float f32x4;

#define NB 8
#define CH 192

static __device__ __forceinline__ float bf2f(bf16 v){ return __bfloat162float(v); }
static __device__ __forceinline__ u16 f2bu(float f){
  union { bf16 h; u16 u; } cv; cv.h = __float2bfloat16(f); return cv.u;
}

// ---------------- utility kernels ----------------

__global__ void k_zero(float* p, int n){
  int i = blockIdx.x*blockDim.x + threadIdx.x;
  if(i < n) p[i] = 0.f;
}

__global__ void k_fill(float* p, int n, float v){
  int i = blockIdx.x*blockDim.x + threadIdx.x;
  if(i < n) p[i] = v;
}

// m0[b,256,256] = 1 - mask[b, (y/16)*16 + (x/16)]   (mask: int32 0/1)
__global__ void k_mask0(const int* __restrict__ mask, u8* __restrict__ m0){
  int i = blockIdx.x*blockDim.x + threadIdx.x;
  if(i >= NB*65536) return;
  int b = i >> 16; int p = i & 65535;
  int y = p >> 8, x = p & 255;
  int patch = (y >> 4)*16 + (x >> 4);
  m0[i] = (u8)(1 - mask[b*256 + patch]);
}

// 3x3 stride-2 pad-1 max-pool of mask
__global__ void k_maskdown(const u8* __restrict__ mi, u8* __restrict__ mo,
                           int Ho, int Wo, int Hi, int Wi){
  int i = blockIdx.x*blockDim.x + threadIdx.x;
  int total = NB*Ho*Wo; if(i >= total) return;
  int b = i/(Ho*Wo); int p = i%(Ho*Wo);
  int oy = p/Wo, ox = p%Wo;
  u8 v = 0;
  for(int ky=0; ky<3; ky++){
    int iy = oy*2 + ky - 1; if(iy < 0 || iy >= Hi) continue;
    for(int kx=0; kx<3; kx++){
      int ix = ox*2 + kx - 1; if(ix < 0 || ix >= Wi) continue;
      u8 t = mi[(b*Hi + iy)*Wi + ix]; if(t > v) v = t;
    }
  }
  mo[i] = v;
}

__global__ void k_count(const u8* __restrict__ m, int n, float* cnt){
  int i = blockIdx.x*blockDim.x + threadIdx.x;
  int stride = gridDim.x*blockDim.x;
  int local = 0;
  for(int j=i; j<n; j+=stride) local += m[j];
  for(int o=32; o>0; o>>=1) local += __shfl_down(local, o, 64);
  if((threadIdx.x & 63) == 0 && local) atomicAdd(cnt, (float)local);
}

// ---------------- stem BN stats: block = (channel, pixel-chunk), images f32 ----------------

__global__ __launch_bounds__(256) void k_stemstats2(const float* __restrict__ im,
        const u8* __restrict__ m0, const float* __restrict__ sw,
        float* __restrict__ stats){
  int c = blockIdx.x;          // 0..191
  int chunk = blockIdx.y;      // 0..127, 4096 px each
  float w0 = sw[c*3+0], w1 = sw[c*3+1], w2 = sw[c*3+2];
  float s = 0.f, s2 = 0.f;
  int start = chunk*4096;
  for(int j = start + threadIdx.x; j < start + 4096; j += 256){
    if(m0[j]){
      int b = j >> 16, p = j & 65535;
      float d = w0*im[(size_t)(b*3+0)*65536 + p]
              + w1*im[(size_t)(b*3+1)*65536 + p]
              + w2*im[(size_t)(b*3+2)*65536 + p];
      s += d; s2 += d*d;
    }
  }
  for(int o=32; o>0; o>>=1){ s += __shfl_down(s, o, 64); s2 += __shfl_down(s2, o, 64); }
  __shared__ float sh[8];
  int w = threadIdx.x >> 6;
  if((threadIdx.x & 63) == 0){ sh[w] = s; sh[4+w] = s2; }
  __syncthreads();
  if(threadIdx.x == 0){
    float ts = 0.f, t2 = 0.f;
    for(int k=0;k<4;k++){ ts += sh[k]; t2 += sh[4+k]; }
    atomicAdd(&stats[c], ts);
    atomicAdd(&stats[CH + c], t2);
  }
}

// fold stem BN into stem weights: swf[c] = {sc*w0, sc*w1, sc*w2, shift}
__global__ void k_fold(const float* __restrict__ sw, const float* __restrict__ ssA,
                       float* __restrict__ swf){
  int c = threadIdx.x; if(c >= CH) return;
  float sc = ssA[c];
  swf[c*4+0] = sc*sw[c*3+0];
  swf[c*4+1] = sc*sw[c*3+1];
  swf[c*4+2] = sc*sw[c*3+2];
  swf[c*4+3] = ssA[CH+c];
}

// bf16 weight repack: W[co,ci,3,3] f32 -> Wb[tap][co][ci]  (B^T layout for MFMA)
__global__ void k_repackb(const float* __restrict__ w, bf16* __restrict__ wb){
  int i = blockIdx.x*blockDim.x + threadIdx.x;
  if(i >= CH*CH*9) return;
  int tap = i % 9; int ci = (i/9) % CH; int co = i/(9*CH);
  wb[(size_t)tap*CH*CH + co*CH + ci] = __float2bfloat16(w[i]);
}

// ================= MFMA implicit-GEMM convs =================
// All: block = 256 thr (4 waves), one 8x8 output tile, all 192 co.
// GEMM M=64 sites, N=192 co, K=9 taps x 192 ci (chunks of 32).
// C/D layout (verified): row=(lane>>4)*4+reg -> site, col=lane&15 -> co.

// ---- stride-1: LDS input tile [y][x][ci] 10x10x200 bf16 (40 KB), full 192 ci ----
#define CIP 200
__global__ __launch_bounds__(256) void k_convm(const bf16* __restrict__ in,
        const bf16* __restrict__ wb, const u8* __restrict__ mk,
        bf16* __restrict__ out, int Ho, int Wo){
  __shared__ __align__(16) u16 tile[10*10*CIP];
  __shared__ int anyact;
  const int t = threadIdx.x;
  const int b = blockIdx.z;
  const int ox0 = blockIdx.x*8, oy0 = blockIdx.y*8;

  if(t == 0) anyact = 0;
  __syncthreads();
  if(t < 64){
    int r = t >> 3, c = t & 7;
    if(mk[(b*Ho + oy0 + r)*Wo + ox0 + c]) anyact = 1;
  }
  __syncthreads();
  if(!anyact) return;

  const int gy0 = oy0 - 1, gx0 = ox0 - 1;
  for(int rr = t; rr < CH*10; rr += 256){
    int ci = rr/10, y = rr%10;
    int gy = gy0 + y;
    const u16* ib = (const u16*)(in + ((size_t)(b*CH + ci)*Ho + gy)*Wo);
    u16* ld = &tile[(y*10)*CIP + ci];
    bool rowok = (gy >= 0 && gy < Ho);
#pragma unroll
    for(int x=0; x<10; x++){
      int gx = gx0 + x;
      u16 v = 0;
      if(rowok && gx >= 0 && gx < Wo) v = ib[gx];
      ld[x*CIP] = v;
    }
  }
  __syncthreads();

  const int w = t >> 6;
  const int l = t & 63;
  const int l15 = l & 15, q = l >> 4;
  f32x4 acc[4][3];
#pragma unroll
  for(int mt=0;mt<4;mt++)
#pragma unroll
    for(int nt=0;nt<3;nt++) acc[mt][nt] = (f32x4){0.f,0.f,0.f,0.f};

  int sy[4], sx[4];
#pragma unroll
  for(int mt=0;mt<4;mt++){ int s = mt*16 + l15; sy[mt] = s>>3; sx[mt] = s&7; }
  const int co0 = w*48;

  for(int tap=0; tap<9; tap++){
    const int ky = tap/3, kx = tap%3;
    const u16* tb[4];
#pragma unroll
    for(int mt=0;mt<4;mt++)
      tb[mt] = &tile[((sy[mt]+ky)*10 + sx[mt]+kx)*CIP + q*8];
    const u16* wt0 = (const u16*)(wb + (size_t)tap*CH*CH);
#pragma unroll
    for(int c=0;c<6;c++){
      bf16x8 a[4], bb[3];
#pragma unroll
      for(int mt=0;mt<4;mt++) a[mt] = *(const bf16x8*)(tb[mt] + c*32);
#pragma unroll
      for(int nt=0;nt<3;nt++){
        int co = co0 + nt*16 + l15;
        bb[nt] = *(const bf16x8*)(wt0 + co*CH + c*32 + q*8);
      }
#pragma unroll
      for(int mt=0;mt<4;mt++)
#pragma unroll
        for(int nt=0;nt<3;nt++)
          acc[mt][nt] = __builtin_amdgcn_mfma_f32_16x16x32_bf16(a[mt], bb[nt], acc[mt][nt], 0, 0, 0);
    }
  }

  __syncthreads();
  u16* obuf = tile;
#pragma unroll
  for(int mt=0;mt<4;mt++){
#pragma unroll
    for(int nt=0;nt<3;nt++){
      int co = co0 + nt*16 + l15;
#pragma unroll
      for(int r=0;r<4;r++){
        int site = mt*16 + q*4 + r;
        obuf[co*68 + site] = f2bu(acc[mt][nt][r]);
      }
    }
  }
  __syncthreads();
  for(int c=t; c<CH*16; c+=256){
    int co = c >> 4; int rem = c & 15; int r = rem >> 1; int xh = (rem & 1)*4;
    ushort4 v = *(const ushort4*)&obuf[co*68 + r*8 + xh];
    *(ushort4*)((u16*)out + ((size_t)(b*CH + co)*Ho + oy0 + r)*Wo + ox0 + xh) = v;
  }
}

// ---- stride-2 (generic bf16 input): LDS [y][x][ci_half] 17x17x104, ci in 2 halves of 96 ----
#define CIP2 104
__global__ __launch_bounds__(256) void k_convms2(const bf16* __restrict__ in,
        const bf16* __restrict__ wb, const u8* __restrict__ mk,
        bf16* __restrict__ out, int Ho, int Wo){
  __shared__ __align__(16) u16 tile[17*17*CIP2];   // 60112 B
  __shared__ int anyact;
  const int t = threadIdx.x;
  const int b = blockIdx.z;
  const int ox0 = blockIdx.x*8, oy0 = blockIdx.y*8;
  const int Hi = Ho*2, Wi = Wo*2;

  if(t == 0) anyact = 0;
  __syncthreads();
  if(t < 64){
    int r = t >> 3, c = t & 7;
    if(mk[(b*Ho + oy0 + r)*Wo + ox0 + c]) anyact = 1;
  }
  __syncthreads();
  if(!anyact) return;

  const int w = t >> 6;
  const int l = t & 63;
  const int l15 = l & 15, q = l >> 4;
  f32x4 acc[4][3];
#pragma unroll
  for(int mt=0;mt<4;mt++)
#pragma unroll
    for(int nt=0;nt<3;nt++) acc[mt][nt] = (f32x4){0.f,0.f,0.f,0.f};

  int siy[4], six[4];
#pragma unroll
  for(int mt=0;mt<4;mt++){ int s = mt*16 + l15; siy[mt] = (s>>3)*2; six[mt] = (s&7)*2; }
  const int co0 = w*48;
  const int gy0 = oy0*2 - 1, gx0 = ox0*2 - 1;

  for(int h=0; h<2; h++){
    __syncthreads();
    // stage half: (ci_local 0..95, y 0..16) pairs, 17 x each
    for(int rr = t; rr < 96*17; rr += 256){
      int cil = rr/17, y = rr%17;
      int ci = h*96 + cil;
      int gy = gy0 + y;
      const u16* ib = (const u16*)(in + ((size_t)(b*CH + ci)*Hi + gy)*Wi);
      u16* ld = &tile[(y*17)*CIP2 + cil];
      bool rowok = (gy >= 0 && gy < Hi);
#pragma unroll
      for(int x=0; x<17; x++){
        int gx = gx0 + x;
        u16 v = 0;
        if(rowok && gx >= 0 && gx < Wi) v = ib[gx];
        ld[x*CIP2] = v;
      }
    }
    __syncthreads();
    for(int tap=0; tap<9; tap++){
      const int ky = tap/3, kx = tap%3;
      const u16* tb[4];
#pragma unroll
      for(int mt=0;mt<4;mt++)
        tb[mt] = &tile[((siy[mt]+ky)*17 + six[mt]+kx)*CIP2 + q*8];
      const u16* wt0 = (const u16*)(wb + (size_t)tap*CH*CH);
#pragma unroll
      for(int c=0;c<3;c++){
        bf16x8 a[4], bb[3];
#pragma unroll
        for(int mt=0;mt<4;mt++) a[mt] = *(const bf16x8*)(tb[mt] + c*32);
#pragma unroll
        for(int nt=0;nt<3;nt++){
          int co = co0 + nt*16 + l15;
          bb[nt] = *(const bf16x8*)(wt0 + co*CH + h*96 + c*32 + q*8);
        }
#pragma unroll
        for(int mt=0;mt<4;mt++)
#pragma unroll
          for(int nt=0;nt<3;nt++)
            acc[mt][nt] = __builtin_amdgcn_mfma_f32_16x16x32_bf16(a[mt], bb[nt], acc[mt][nt], 0, 0, 0);
      }
    }
  }

  __syncthreads();
  u16* obuf = tile;
#pragma unroll
  for(int mt=0;mt<4;mt++){
#pragma unroll
    for(int nt=0;nt<3;nt++){
      int co = co0 + nt*16 + l15;
#pragma unroll
      for(int r=0;r<4;r++){
        int site = mt*16 + q*4 + r;
        obuf[co*68 + site] = f2bu(acc[mt][nt][r]);
      }
    }
  }
  __syncthreads();
  for(int c=t; c<CH*16; c+=256){
    int co = c >> 4; int rem = c & 15; int r = rem >> 1; int xh = (rem & 1)*4;
    ushort4 v = *(const ushort4*)&obuf[co*68 + r*8 + xh];
    *(ushort4*)((u16*)out + ((size_t)(b*CH + co)*Ho + oy0 + r)*Wo + ox0 + xh) = v;
  }
}

// ---- stage-0 (256->128, s2) with fused stem: stem BN folded into swf ----
__global__ __launch_bounds__(256) void k_conv0m(const float* __restrict__ im,
        const float* __restrict__ swf, const u8* __restrict__ m0,
        const bf16* __restrict__ wb, const u8* __restrict__ mk,
        bf16* __restrict__ out){
  __shared__ __align__(16) u16 tile[17*17*CIP2];   // 60112 B
  __shared__ float rgbs[3][292];
  __shared__ u8 mts[292];
  __shared__ int anyact;
  const int t = threadIdx.x;
  const int b = blockIdx.z;
  const int ox0 = blockIdx.x*8, oy0 = blockIdx.y*8;

  if(t == 0) anyact = 0;
  __syncthreads();
  if(t < 64){
    int r = t >> 3, c = t & 7;
    if(mk[(b*128 + oy0 + r)*128 + ox0 + c]) anyact = 1;
  }
  __syncthreads();
  if(!anyact) return;

  const int gy0 = oy0*2 - 1, gx0 = ox0*2 - 1;
  for(int e=t; e<289; e+=256){
    int r = e/17, c = e%17;
    int gy = gy0 + r, gx = gx0 + c;
    float r_=0.f, g_=0.f, bl=0.f; u8 mv=0;
    if(gy >= 0 && gy < 256 && gx >= 0 && gx < 256){
      int pi = gy*256 + gx;
      mv = m0[b*65536 + pi];
      r_ = im[(size_t)(b*3+0)*65536 + pi];
      g_ = im[(size_t)(b*3+1)*65536 + pi];
      bl = im[(size_t)(b*3+2)*65536 + pi];
    }
    rgbs[0][e]=r_; rgbs[1][e]=g_; rgbs[2][e]=bl; mts[e]=mv;
  }

  const int w = t >> 6;
  const int l = t & 63;
  const int l15 = l & 15, q = l >> 4;
  f32x4 acc[4][3];
#pragma unroll
  for(int mt=0;mt<4;mt++)
#pragma unroll
    for(int nt=0;nt<3;nt++) acc[mt][nt] = (f32x4){0.f,0.f,0.f,0.f};

  int siy[4], six[4];
#pragma unroll
  for(int mt=0;mt<4;mt++){ int s = mt*16 + l15; siy[mt] = (s>>3)*2; six[mt] = (s&7)*2; }
  const int co0 = w*48;

  for(int h=0; h<2; h++){
    __syncthreads();
    // stage half: stem output = relu(fma3(rgb) + shift), 0 at masked sites
    for(int e=t; e<96*289; e+=256){
      int cil = e/289, site = e%289;
      int ci = h*96 + cil;
      float4 wf = *(const float4*)&swf[ci*4];
      float d = wf.x*rgbs[0][site] + wf.y*rgbs[1][site] + wf.z*rgbs[2][site] + wf.w;
      float a = mts[site] ? fmaxf(d, 0.f) : 0.f;
      tile[site*CIP2 + cil] = f2bu(a);
    }
    __syncthreads();
    for(int tap=0; tap<9; tap++){
      const int ky = tap/3, kx = tap%3;
      const u16* tb[4];
#pragma unroll
      for(int mt=0;mt<4;mt++)
        tb[mt] = &tile[((siy[mt]+ky)*17 + six[mt]+kx)*CIP2 + q*8];
      const u16* wt0 = (const u16*)(wb + (size_t)tap*CH*CH);
#pragma unroll
      for(int c=0;c<3;c++){
        bf16x8 a[4], bb[3];
#pragma unroll
        for(int mt=0;mt<4;mt++) a[mt] = *(const bf16x8*)(tb[mt] + c*32);
#pragma unroll
        for(int nt=0;nt<3;nt++){
          int co = co0 + nt*16 + l15;
          bb[nt] = *(const bf16x8*)(wt0 + co*CH + h*96 + c*32 + q*8);
        }
#pragma unroll
        for(int mt=0;mt<4;mt++)
#pragma unroll
          for(int nt=0;nt<3;nt++)
            acc[mt][nt] = __builtin_amdgcn_mfma_f32_16x16x32_bf16(a[mt], bb[nt], acc[mt][nt], 0, 0, 0);
      }
    }
  }

  __syncthreads();
  u16* obuf = tile;
#pragma unroll
  for(int mt=0;mt<4;mt++){
#pragma unroll
    for(int nt=0;nt<3;nt++){
      int co = co0 + nt*16 + l15;
#pragma unroll
      for(int r=0;r<4;r++){
        int site = mt*16 + q*4 + r;
        obuf[co*68 + site] = f2bu(acc[mt][nt][r]);
      }
    }
  }
  __syncthreads();
  for(int c=t; c<CH*16; c+=256){
    int co = c >> 4; int rem = c & 15; int r = rem >> 1; int xh = (rem & 1)*4;
    ushort4 v = *(const ushort4*)&obuf[co*68 + r*8 + xh];
    *(ushort4*)((u16*)out + ((size_t)(b*CH + co)*128 + oy0 + r)*128 + ox0 + xh) = v;
  }
}

// ---------------- masked BN: stats / finalize / apply ----------------

__global__ void k_bnstats(const bf16* __restrict__ x, const u8* __restrict__ m,
                          float* __restrict__ stats, int HW){
  int c = blockIdx.x;
  int nchunk = gridDim.y;
  int nper = (NB*HW + nchunk - 1)/nchunk;
  int start = blockIdx.y*nper;
  int end = start + nper; if(end > NB*HW) end = NB*HW;
  float s = 0.f, s2 = 0.f;
  for(int i = start + threadIdx.x; i < end; i += blockDim.x){
    int b = i / HW, p = i % HW;
    if(m[b*HW + p]){
      float v = bf2f(x[(size_t)(b*CH + c)*HW + p]);
      s += v; s2 += v*v;
    }
  }
  for(int o=32; o>0; o>>=1){ s += __shfl_down(s, o, 64); s2 += __shfl_down(s2, o, 64); }
  __shared__ float sh[8];
  int w = threadIdx.x >> 6;
  if((threadIdx.x & 63) == 0){ sh[w] = s; sh[4+w] = s2; }
  __syncthreads();
  if(threadIdx.x == 0){
    float ts = 0.f, t2 = 0.f;
    int nw = blockDim.x >> 6;
    for(int k=0;k<nw;k++){ ts += sh[k]; t2 += sh[4+k]; }
    atomicAdd(&stats[c], ts);
    atomicAdd(&stats[CH + c], t2);
  }
}

__global__ void k_bnfinal(const float* __restrict__ stats, const float* __restrict__ cnt,
                          const float* __restrict__ g, const float* __restrict__ bb,
                          float* __restrict__ ss){
  int c = threadIdx.x; if(c >= CH) return;
  float n = fmaxf(*cnt, 1.0f);
  float mean = stats[c]/n;
  float var = stats[CH + c]/n - mean*mean;
  var = fmaxf(var, 0.f);
  float rstd = rsqrtf(var + 1e-5f);
  float sc = g[c]*rstd;
  ss[c] = sc;
  ss[CH + c] = bb[c] - mean*sc;
}

template<int RELU, int ADD>
__global__ void k_bnapply(const bf16* __restrict__ x, const u8* __restrict__ m,
                          const float* __restrict__ ss, const bf16* __restrict__ idn,
                          bf16* __restrict__ out, int HW){
  int i = blockIdx.x*blockDim.x + threadIdx.x;
  int total = NB*CH*HW; if(i >= total) return;
  int p = i % HW; int c = (i/HW) % CH; int b = i/(HW*CH);
  float v = bf2f(x[i])*ss[c] + ss[CH + c];
  v *= (float)m[b*HW + p];
  if(ADD) v += bf2f(idn[i]);
  if(RELU) v = fmaxf(v, 0.f);
  out[i] = __float2bfloat16(v);
}

// final BN apply: relu, no add, float32 output (x region of d_out)
__global__ void k_bnapply_out(const bf16* __restrict__ x, const u8* __restrict__ m,
                              const float* __restrict__ ss, float* __restrict__ out, int HW){
  int i = blockIdx.x*blockDim.x + threadIdx.x;
  int total = NB*CH*HW; if(i >= total) return;
  int p = i % HW; int c = (i/HW) % CH; int b = i/(HW*CH);
  float v = bf2f(x[i])*ss[c] + ss[CH + c];
  v *= (float)m[b*HW + p];
  v = fmaxf(v, 0.f);
  out[i] = v;
}

// ---------------- final 1x1 conv (192 -> 192) at 16x16 ----------------

__global__ void k_final(const bf16* __restrict__ in, const float* __restrict__ w,
                        const u8* __restrict__ m4, bf16* __restrict__ out){
  int i = blockIdx.x*blockDim.x + threadIdx.x;
  if(i >= NB*CH*256) return;
  int p = i & 255; int co = (i >> 8) % CH; int b = i/(256*CH);
  if(!m4[b*256 + p]) return;
  float acc = 0.f;
  for(int ci=0; ci<CH; ci++)
    acc += w[co*CH + ci]*bf2f(in[(b*CH + ci)*256 + p]);
  out[i] = __float2bfloat16(acc);
}

// ---------------- tail: mask + ids_restore outputs (float32) ----------------

__global__ void k_tail(const int* __restrict__ mask, float* __restrict__ out){
  int i = blockIdx.x*blockDim.x + threadIdx.x;
  if(i < 2048){
    out[393216 + i] = (float)mask[i];
  } else if(i < 4096){
    int j = i - 2048;
    out[395264 + j] = (float)(j & 255);
  }
}

// ---------------- host orchestration ----------------

extern "C" void kernel_launch(void* const* d_in, const int* in_sizes, int n_in,
                              void* d_out, int out_size, void* d_ws, size_t ws_size,
                              hipStream_t stream){
  const float* images = (const float*)d_in[0];
  const int*   maskI  = (const int*)d_in[1];
  const float* stem_w = (const float*)d_in[2];
  const float* stem_g = (const float*)d_in[3];
  const float* stem_b = (const float*)d_in[4];
  const float* dw1 = (const float*)d_in[5];
  const float* dg1 = (const float*)d_in[6];
  const float* db1 = (const float*)d_in[7];
  const float* dw2 = (const float*)d_in[8];
  const float* dg2 = (const float*)d_in[9];
  const float* db2 = (const float*)d_in[10];
  const float* rw1 = (const float*)d_in[11];
  const float* rg1 = (const float*)d_in[12];
  const float* rb1 = (const float*)d_in[13];
  const float* rw2 = (const float*)d_in[14];
  const float* rg2 = (const float*)d_in[15];
  const float* rb2 = (const float*)d_in[16];
  const float* final_w = (const float*)d_in[17];
  const float* final_g = (const float*)d_in[18];
  const float* final_b = (const float*)d_in[19];
  float* outF = (float*)d_out;

  // workspace carve (~153 MB); activations stored bf16 internally
  char* wsp = (char*)d_ws;
  auto alloc = [&](size_t bytes)->char*{
    char* p = wsp; wsp += (bytes + 255) & ~(size_t)255; return p;
  };
  bf16* S0 = (bf16*)alloc((size_t)NB*CH*16384*2);
  bf16* S1 = (bf16*)alloc((size_t)NB*CH*16384*2);
  bf16* S2 = (bf16*)alloc((size_t)NB*CH*16384*2);
  int Hs[5] = {256,128,64,32,16};
  u8* M[5];
  for(int l=0;l<5;l++) M[l] = (u8*)alloc((size_t)NB*Hs[l]*Hs[l]);
  bf16*  Wb  = (bf16*)alloc((size_t)CH*CH*9*2);
  float* swf = (float*)alloc(CH*4*4);
  float* stats = (float*)alloc(2*CH*4);
  float* ss    = (float*)alloc(2*CH*4);
  float* ssA   = (float*)alloc(2*CH*4);
  float* cnts  = (float*)alloc(8*4);
  size_t need = (size_t)(wsp - (char*)d_ws);

  if(ws_size < need){
    k_fill<<<(393216+255)/256, 256, 0, stream>>>(outF, 393216, 777.0f);
    k_tail<<<16, 256, 0, stream>>>(maskI, outF);
    return;
  }

  // ---- mask pyramid + counts ----
  k_mask0<<<(NB*65536+255)/256, 256, 0, stream>>>(maskI, M[0]);
  for(int l=1;l<5;l++){
    int total = NB*Hs[l]*Hs[l];
    k_maskdown<<<(total+255)/256, 256, 0, stream>>>(M[l-1], M[l], Hs[l], Hs[l], Hs[l-1], Hs[l-1]);
  }
  k_zero<<<1, 32, 0, stream>>>(cnts, 8);
  for(int l=0;l<5;l++){
    int n = NB*Hs[l]*Hs[l];
    int blocks = (n + 256*64 - 1)/(256*64); if(blocks < 1) blocks = 1; if(blocks > 256) blocks = 256;
    k_count<<<blocks, 256, 0, stream>>>(M[l], n, cnts + l);
  }

  // ---- stem BN params + fold into stem weights ----
  k_zero<<<2, 256, 0, stream>>>(stats, 2*CH);
  k_stemstats2<<<dim3(CH, 128), 256, 0, stream>>>(images, M[0], stem_w, stats);
  k_bnfinal<<<1, CH, 0, stream>>>(stats, cnts + 0, stem_g, stem_b, ssA);
  k_fold<<<1, CH, 0, stream>>>(stem_w, ssA, swf);

  // masked-BN sequence helper (levels 1..4), bf16 in/out
  auto bn = [&](const bf16* x, int lvl, const float* g, const float* bb,
                int relu, const bf16* idn, bf16* outp){
    int HW = Hs[lvl]*Hs[lvl];
    int total = NB*CH*HW;
    k_zero<<<2, 256, 0, stream>>>(stats, 2*CH);
    int nch = (NB*HW)/65536; if(nch < 1) nch = 1;
    k_bnstats<<<dim3(CH, nch), 256, 0, stream>>>(x, M[lvl], stats, HW);
    k_bnfinal<<<1, CH, 0, stream>>>(stats, cnts + lvl, g, bb, ss);
    int blocks = (total + 255)/256;
    if(idn)          k_bnapply<1,1><<<blocks, 256, 0, stream>>>(x, M[lvl], ss, idn, outp, HW);
    else if(relu)    k_bnapply<1,0><<<blocks, 256, 0, stream>>>(x, M[lvl], ss, nullptr, outp, HW);
    else             k_bnapply<0,0><<<blocks, 256, 0, stream>>>(x, M[lvl], ss, nullptr, outp, HW);
  };

  // conv router: all 3x3 convs are MFMA implicit GEMM now
  auto conv = [&](const bf16* inp, const float* wsrc, int Ho, int stride,
                  bf16* outp, const u8* mk){
    k_repackb<<<(CH*CH*9+255)/256, 256, 0, stream>>>(wsrc, Wb);
    dim3 g(Ho/8, Ho/8, NB);
    if(stride == 1) k_convm<<<g, 256, 0, stream>>>(inp, Wb, mk, outp, Ho, Ho);
    else            k_convms2<<<g, 256, 0, stream>>>(inp, Wb, mk, outp, Ho, Ho);
  };

  // ---- 4 stages; rotation: A=S0 always, B alternates, C2 = last-conv scratch ----
  bf16* X = nullptr;
  const int WSZ = CH*CH*9;
  for(int i=0;i<4;i++){
    int Ho = Hs[i+1];
    const u8* mk = M[i+1];
    bf16* A = S0;
    bf16* B = (i % 2 == 0) ? S1 : S2;
    bf16* C2 = (i == 0) ? S2 : X;

    if(i == 0){
      k_repackb<<<(CH*CH*9+255)/256, 256, 0, stream>>>(dw1, Wb);
      dim3 g(16, 16, NB);
      k_conv0m<<<g, 256, 0, stream>>>(images, swf, M[0], Wb, M[1], A);
    } else {
      conv(X, dw1 + (size_t)i*WSZ, Ho, 2, A, mk);
    }
    bn(A, i+1, dg1 + i*CH, db1 + i*CH, 1, nullptr, A);
    conv(A, dw2 + (size_t)i*WSZ, Ho, 1, B, mk);
    bn(B, i+1, dg2 + i*CH, db2 + i*CH, 0, nullptr, B);
    conv(B, rw1 + (size_t)i*WSZ, Ho, 1, A, mk);
    bn(A, i+1, rg1 + i*CH, rb1 + i*CH, 1, nullptr, A);
    conv(A, rw2 + (size_t)i*WSZ, Ho, 1, C2, mk);
    bn(C2, i+1, rg2 + i*CH, rb2 + i*CH, 1, B, B);  // relu(bn*m + idn) -> B
    X = B;
  }

  // ---- final 1x1 + BN + ReLU -> d_out (float32) ----
  k_final<<<(NB*CH*256 + 255)/256, 256, 0, stream>>>(X, final_w, M[4], S0);
  {
    k_zero<<<2, 256, 0, stream>>>(stats, 2*CH);
    k_bnstats<<<dim3(CH, 1), 256, 0, stream>>>(S0, M[4], stats, 256);
    k_bnfinal<<<1, CH, 0, stream>>>(stats, cnts + 4, final_g, final_b, ss);
    int total = NB*CH*256;
    k_bnapply_out<<<(total+255)/256, 256, 0, stream>>>(S0, M[4], ss, outF, 256);
  }

  // ---- tail: mask + ids_restore (float32) ----
  k_tail<<<16, 256, 0, stream>>>(maskI, outF);
}